// Round 1
// baseline (370.731 us; speedup 1.0000x reference)
//
#include <hip/hip_runtime.h>
#include <cstdint>

// ---------------------------------------------------------------------------
// GCN forward: 2x (GEMM 64x64 -> symmetric-norm edge aggregation -> bias+ReLU)
// then global mean pool (sorted batch) and 64x10 FC.
//
// Strategy: build CSR-by-destination every call (histogram + scan + counting
// sort, int atomics only), then gather-based aggregation (no float atomics on
// the wide data). Fold dinv into the GEMM output: g = (h @ W) * dinv[row];
// out[c] = relu(dinv[c]*(g[c] + sum_{e->c} g[src]) + b).
// ---------------------------------------------------------------------------

static __device__ __forceinline__ float breadlane(float v, int k) {
    return __int_as_float(__builtin_amdgcn_readlane(__float_as_int(v), k));
}

__global__ __launch_bounds__(256) void count_k(const int* __restrict__ ecol,
                                               unsigned int* __restrict__ cnt, int E) {
    int e = blockIdx.x * 256 + threadIdx.x;
    if (e < E) atomicAdd(&cnt[ecol[e]], 1u);
}

__global__ __launch_bounds__(256) void dinv_k(const unsigned int* __restrict__ cnt,
                                              float* __restrict__ dinv, int N) {
    int i = blockIdx.x * 256 + threadIdx.x;
    if (i < N) dinv[i] = rsqrtf((float)cnt[i] + 1.0f);  // +1 self loop, always > 0
}

__global__ __launch_bounds__(256) void block_sums_k(const unsigned int* __restrict__ cnt,
                                                    unsigned int* __restrict__ bsum, int N) {
    __shared__ unsigned int s[256];
    int t = threadIdx.x;
    int i = blockIdx.x * 256 + t;
    s[t] = (i < N) ? cnt[i] : 0u;
    __syncthreads();
    for (int d = 128; d > 0; d >>= 1) {
        if (t < d) s[t] += s[t + d];
        __syncthreads();
    }
    if (t == 0) bsum[blockIdx.x] = s[0];
}

__global__ __launch_bounds__(512) void scan_partials_k(const unsigned int* __restrict__ bsum,
                                                       unsigned int* __restrict__ boff, int nb) {
    __shared__ unsigned int s[512];
    int t = threadIdx.x;
    unsigned int v = (t < nb) ? bsum[t] : 0u;
    s[t] = v;
    __syncthreads();
    for (int d = 1; d < 512; d <<= 1) {
        unsigned int u = (t >= d) ? s[t - d] : 0u;
        __syncthreads();
        s[t] += u;
        __syncthreads();
    }
    if (t < nb) boff[t] = s[t] - v;  // exclusive
}

__global__ __launch_bounds__(256) void scan_final_k(const unsigned int* __restrict__ cnt,
                                                    const unsigned int* __restrict__ boff,
                                                    unsigned int* __restrict__ offs,
                                                    unsigned int* __restrict__ cursor, int N) {
    __shared__ unsigned int s[256];
    int t = threadIdx.x;
    int i = blockIdx.x * 256 + t;
    unsigned int v = (i < N) ? cnt[i] : 0u;
    s[t] = v;
    __syncthreads();
    for (int d = 1; d < 256; d <<= 1) {
        unsigned int u = (t >= d) ? s[t - d] : 0u;
        __syncthreads();
        s[t] += u;
        __syncthreads();
    }
    if (i < N) {
        unsigned int e = boff[blockIdx.x] + s[t] - v;  // exclusive scan value
        offs[i] = e;
        cursor[i] = e;
    }
}

__global__ __launch_bounds__(256) void fill_k(const int* __restrict__ erow,
                                              const int* __restrict__ ecol,
                                              unsigned int* __restrict__ cursor,
                                              unsigned int* __restrict__ srcs, int E) {
    int e = blockIdx.x * 256 + threadIdx.x;
    if (e < E) {
        unsigned int p = atomicAdd(&cursor[ecol[e]], 1u);
        srcs[p] = (unsigned int)erow[e];
    }
}

// g[r][c] = (X[r,:] @ W[:,c]) * dinv[r]; lane c holds W[:,c] in registers,
// broadcast X[r][k] via v_readlane.
__global__ __launch_bounds__(256) void gemm_scale_k(const float* __restrict__ X,
                                                    const float* __restrict__ W,
                                                    const float* __restrict__ dinv,
                                                    float* __restrict__ G, int N) {
    const int lane = threadIdx.x & 63;
    float w[64];
#pragma unroll
    for (int k = 0; k < 64; ++k) w[k] = W[k * 64 + lane];
    const int wid = blockIdx.x * (blockDim.x >> 6) + (threadIdx.x >> 6);
    const int nw = gridDim.x * (blockDim.x >> 6);
    for (int r = wid * 2; r < N; r += nw * 2) {
        const int r1 = r + 1;
        float xa = X[(size_t)r * 64 + lane];
        float xb = (r1 < N) ? X[(size_t)r1 * 64 + lane] : 0.0f;
        float a0 = 0.f, a1 = 0.f, a2 = 0.f, a3 = 0.f;
        float c0 = 0.f, c1 = 0.f, c2 = 0.f, c3 = 0.f;
#pragma unroll
        for (int k = 0; k < 64; k += 4) {
            a0 = fmaf(breadlane(xa, k + 0), w[k + 0], a0);
            a1 = fmaf(breadlane(xa, k + 1), w[k + 1], a1);
            a2 = fmaf(breadlane(xa, k + 2), w[k + 2], a2);
            a3 = fmaf(breadlane(xa, k + 3), w[k + 3], a3);
            c0 = fmaf(breadlane(xb, k + 0), w[k + 0], c0);
            c1 = fmaf(breadlane(xb, k + 1), w[k + 1], c1);
            c2 = fmaf(breadlane(xb, k + 2), w[k + 2], c2);
            c3 = fmaf(breadlane(xb, k + 3), w[k + 3], c3);
        }
        G[(size_t)r * 64 + lane] = (a0 + a1 + a2 + a3) * dinv[r];
        if (r1 < N) G[(size_t)r1 * 64 + lane] = (c0 + c1 + c2 + c3) * dinv[r1];
    }
}

// H[node][c] = relu(dinv[node] * (G[node][c] + sum_{src in CSR[node]} G[src][c]) + b[c])
__global__ __launch_bounds__(256) void agg_k(const float* __restrict__ G,
                                             const unsigned int* __restrict__ offs,
                                             const unsigned int* __restrict__ cnt,
                                             const unsigned int* __restrict__ srcs,
                                             const float* __restrict__ dinv,
                                             const float* __restrict__ bias,
                                             float* __restrict__ H, int N) {
    const int lane = threadIdx.x & 63;
    const int node = blockIdx.x * (blockDim.x >> 6) + (threadIdx.x >> 6);
    if (node >= N) return;
    float acc = G[(size_t)node * 64 + lane];  // self loop
    const unsigned int o = offs[node];
    const unsigned int c = cnt[node];
    unsigned int j = 0;
    for (; j + 4 <= c; j += 4) {
        unsigned int r0 = srcs[o + j + 0];
        unsigned int r1 = srcs[o + j + 1];
        unsigned int r2 = srcs[o + j + 2];
        unsigned int r3 = srcs[o + j + 3];
        float v0 = G[(size_t)r0 * 64 + lane];
        float v1 = G[(size_t)r1 * 64 + lane];
        float v2 = G[(size_t)r2 * 64 + lane];
        float v3 = G[(size_t)r3 * 64 + lane];
        acc += v0;
        acc += v1;
        acc += v2;
        acc += v3;
    }
    for (; j < c; ++j) acc += G[(size_t)srcs[o + j] * 64 + lane];
    H[(size_t)node * 64 + lane] = fmaxf(fmaf(acc, dinv[node], bias[lane]), 0.0f);
}

// sorted-batch mean pool: running per-wave accumulator, flush on graph change
__global__ __launch_bounds__(256) void pool_k(const float* __restrict__ H,
                                              const int* __restrict__ batch,
                                              float* __restrict__ pooled,
                                              float* __restrict__ cntg, int N) {
    const int c = threadIdx.x & 63;
    const int sub = threadIdx.x >> 6;
    const int base = blockIdx.x * 256;
    const int end = min(base + 256, N);
    float acc = 0.f, cacc = 0.f;
    int cur = -1;
    for (int i = base + sub; i < end; i += 4) {
        int g = batch[i];
        if (g != cur) {
            if (cur >= 0) {
                atomicAdd(&pooled[cur * 64 + c], acc);
                if (c == 0) atomicAdd(&cntg[cur], cacc);
            }
            cur = g;
            acc = 0.f;
            cacc = 0.f;
        }
        acc += H[(size_t)i * 64 + c];
        cacc += 1.f;
    }
    if (cur >= 0) {
        atomicAdd(&pooled[cur * 64 + c], acc);
        if (c == 0) atomicAdd(&cntg[cur], cacc);
    }
}

__global__ __launch_bounds__(64) void fc_k(const float* __restrict__ pooled,
                                           const float* __restrict__ cntg,
                                           const float* __restrict__ Wfc,
                                           const float* __restrict__ bfc,
                                           float* __restrict__ out) {
    __shared__ float p[64];
    const int g = blockIdx.x;
    const int t = threadIdx.x;
    const float cc = fmaxf(cntg[g], 1.0f);
    p[t] = pooled[g * 64 + t] / cc;
    __syncthreads();
    if (t < 10) {
        float a = bfc[t];
#pragma unroll
        for (int k = 0; k < 64; ++k) a = fmaf(p[k], Wfc[k * 10 + t], a);
        out[g * 10 + t] = a;
    }
}

extern "C" void kernel_launch(void* const* d_in, const int* in_sizes, int n_in,
                              void* d_out, int out_size, void* d_ws, size_t ws_size,
                              hipStream_t stream) {
    const float* x    = (const float*)d_in[0];
    const float* W1   = (const float*)d_in[1];
    const float* b1   = (const float*)d_in[2];
    const float* W2   = (const float*)d_in[3];
    const float* b2   = (const float*)d_in[4];
    const float* Wfc  = (const float*)d_in[5];
    const float* bfc  = (const float*)d_in[6];
    const int*   eidx = (const int*)d_in[7];
    const int*   batch = (const int*)d_in[8];

    const int N = in_sizes[0] / 64;
    const int E = in_sizes[7] / 2;
    const int* erow = eidx;       // sources
    const int* ecol = eidx + E;   // destinations

    char* ws = (char*)d_ws;
    size_t off = 0;
    auto alloc = [&](size_t bytes) -> void* {
        void* p = ws + off;
        off = (off + bytes + 511) & ~(size_t)511;
        return p;
    };
    unsigned int* cnt    = (unsigned int*)alloc((size_t)N * 4);
    unsigned int* offs   = (unsigned int*)alloc((size_t)N * 4);
    unsigned int* cursor = (unsigned int*)alloc((size_t)N * 4);
    float*        dinv   = (float*)alloc((size_t)N * 4);
    unsigned int* bsum   = (unsigned int*)alloc(512 * 4);
    unsigned int* boff   = (unsigned int*)alloc(512 * 4);
    unsigned int* srcs   = (unsigned int*)alloc((size_t)E * 4);
    float*        G      = (float*)alloc((size_t)N * 64 * 4);
    float*        H      = (float*)alloc((size_t)N * 64 * 4);
    float*        pooled = (float*)alloc((size_t)(128 * 64 + 128) * 4);
    float*        cntg   = pooled + 128 * 64;

    const int NB = (N + 255) / 256;
    const int EB = (E + 255) / 256;

    // --- degree histogram + dinv ---
    hipMemsetAsync(cnt, 0, (size_t)N * 4, stream);
    hipMemsetAsync(pooled, 0, (size_t)(128 * 64 + 128) * 4, stream);
    count_k<<<EB, 256, 0, stream>>>(ecol, cnt, E);
    dinv_k<<<NB, 256, 0, stream>>>(cnt, dinv, N);

    // --- exclusive scan of cnt -> offs (and cursor) ---
    block_sums_k<<<NB, 256, 0, stream>>>(cnt, bsum, N);
    scan_partials_k<<<1, 512, 0, stream>>>(bsum, boff, NB);
    scan_final_k<<<NB, 256, 0, stream>>>(cnt, boff, offs, cursor, N);

    // --- counting-sort edges by destination ---
    fill_k<<<EB, 256, 0, stream>>>(erow, ecol, cursor, srcs, E);

    // --- layer 1 ---
    gemm_scale_k<<<1024, 256, 0, stream>>>(x, W1, dinv, G, N);
    agg_k<<<(N + 3) / 4, 256, 0, stream>>>(G, offs, cnt, srcs, dinv, b1, H, N);

    // --- layer 2 (reuse G; H(h1) -> G(g2) -> H(h2)) ---
    gemm_scale_k<<<1024, 256, 0, stream>>>(H, W2, dinv, G, N);
    agg_k<<<(N + 3) / 4, 256, 0, stream>>>(G, offs, cnt, srcs, dinv, b2, H, N);

    // --- pooling + FC ---
    pool_k<<<NB, 256, 0, stream>>>(H, batch, pooled, cntg, N);
    fc_k<<<128, 64, 0, stream>>>(pooled, cntg, Wfc, bfc, (float*)d_out);
}

// Round 2
// 241.693 us; speedup vs baseline: 1.5339x; 1.5339x over previous
//
#include <hip/hip_runtime.h>
#include <cstdint>

// ---------------------------------------------------------------------------
// GCN forward: 2x (GEMM 64x64 -> symmetric-norm edge aggregation -> bias+ReLU)
// then global mean pool (sorted batch) and 64x10 FC.
//
// CSR build per call via 2-level bucketed counting sort (LDS atomics only,
// contiguous regional writes) instead of global random atomics:
//   hist_k    : per-block LDS histogram of coarse bucket (dst>>9)
//   scanb_k   : per-bucket exclusive scan over blocks (+ totals)
//   scant_k   : exclusive scan of bucket totals -> bucket base
//   scatter_k : scatter packed (src<<9|fine) into per-(block,bucket) runs
//   fine_k    : per-bucket 512-bin LDS sort -> srcs CSR + cnt/offs/dinv
// Aggregation is gather-based: g = (h @ W) * dinv[row];
//   out[c] = relu(dinv[c]*(g[c] + sum_{e->c} g[src]) + b)   (float4 gathers)
// ---------------------------------------------------------------------------

#define NBLK_SORT 256

static __device__ __forceinline__ float breadlane(float v, int k) {
    return __int_as_float(__builtin_amdgcn_readlane(__float_as_int(v), k));
}

__global__ __launch_bounds__(256) void hist_k(const int* __restrict__ ecol,
                                              unsigned int* __restrict__ bhist,
                                              int E, int chunk, int nbuck) {
    __shared__ unsigned int lh[256];
    lh[threadIdx.x] = 0u;
    __syncthreads();
    const int s = blockIdx.x * chunk;
    const int e = min(s + chunk, E);
    for (int i = s + threadIdx.x; i < e; i += 256)
        atomicAdd(&lh[((unsigned int)ecol[i]) >> 9], 1u);
    __syncthreads();
    if ((int)threadIdx.x < nbuck)
        bhist[blockIdx.x * nbuck + threadIdx.x] = lh[threadIdx.x];
}

// per-bucket exclusive scan across the NBLK_SORT blocks; totals[k] = column sum
__global__ __launch_bounds__(256) void scanb_k(const unsigned int* __restrict__ bhist,
                                               unsigned int* __restrict__ bofs,
                                               unsigned int* __restrict__ totals, int nbuck) {
    __shared__ unsigned int s[256];
    const int k = blockIdx.x;
    const int t = threadIdx.x;
    unsigned int v = bhist[t * nbuck + k];
    s[t] = v;
    __syncthreads();
    for (int d = 1; d < 256; d <<= 1) {
        unsigned int u = (t >= d) ? s[t - d] : 0u;
        __syncthreads();
        s[t] += u;
        __syncthreads();
    }
    bofs[t * nbuck + k] = s[t] - v;
    if (t == 255) totals[k] = s[255];
}

__global__ __launch_bounds__(256) void scant_k(const unsigned int* __restrict__ totals,
                                               unsigned int* __restrict__ base, int nbuck) {
    __shared__ unsigned int s[256];
    const int t = threadIdx.x;
    unsigned int v = (t < nbuck) ? totals[t] : 0u;
    s[t] = v;
    __syncthreads();
    for (int d = 1; d < 256; d <<= 1) {
        unsigned int u = (t >= d) ? s[t - d] : 0u;
        __syncthreads();
        s[t] += u;
        __syncthreads();
    }
    if (t < nbuck) base[t] = s[t] - v;
}

__global__ __launch_bounds__(256) void scatter_k(const int* __restrict__ erow,
                                                 const int* __restrict__ ecol,
                                                 const unsigned int* __restrict__ base,
                                                 const unsigned int* __restrict__ bofs,
                                                 unsigned int* __restrict__ packed,
                                                 int E, int chunk, int nbuck) {
    __shared__ unsigned int cur[256];
    if ((int)threadIdx.x < nbuck)
        cur[threadIdx.x] = base[threadIdx.x] + bofs[blockIdx.x * nbuck + threadIdx.x];
    __syncthreads();
    const int s = blockIdx.x * chunk;
    const int e = min(s + chunk, E);
    for (int i = s + threadIdx.x; i < e; i += 256) {
        unsigned int d = (unsigned int)ecol[i];
        unsigned int k = d >> 9;
        unsigned int p = atomicAdd(&cur[k], 1u);
        packed[p] = (((unsigned int)erow[i]) << 9) | (d & 511u);
    }
}

// one block per bucket: 512-bin fine sort; emits cnt/offs/dinv and srcs
__global__ __launch_bounds__(512) void fine_k(const unsigned int* __restrict__ packed,
                                              const unsigned int* __restrict__ base,
                                              const unsigned int* __restrict__ totals,
                                              unsigned int* __restrict__ cnt,
                                              unsigned int* __restrict__ offs,
                                              float* __restrict__ dinv,
                                              unsigned int* __restrict__ srcs, int N) {
    __shared__ unsigned int fh[512];
    __shared__ unsigned int sc[512];
    const int k = blockIdx.x;
    const int t = threadIdx.x;
    const unsigned int ebase = base[k];
    const unsigned int ecnt = totals[k];
    fh[t] = 0u;
    __syncthreads();
    for (unsigned int j = t; j < ecnt; j += 512)
        atomicAdd(&fh[packed[ebase + j] & 511u], 1u);
    __syncthreads();
    unsigned int v = fh[t];
    sc[t] = v;
    __syncthreads();
    for (int d = 1; d < 512; d <<= 1) {
        unsigned int u = (t >= d) ? sc[t - d] : 0u;
        __syncthreads();
        sc[t] += u;
        __syncthreads();
    }
    const unsigned int excl = sc[t] - v;
    const int node = (k << 9) + t;
    if (node < N) {
        cnt[node] = v;
        offs[node] = ebase + excl;
        dinv[node] = rsqrtf((float)v + 1.0f);  // +1 self loop
    }
    __syncthreads();
    fh[t] = excl;  // reuse as cursor
    __syncthreads();
    for (unsigned int j = t; j < ecnt; j += 512) {
        unsigned int p = packed[ebase + j];
        unsigned int pos = atomicAdd(&fh[p & 511u], 1u);
        srcs[ebase + pos] = p >> 9;
    }
}

// g[r][c] = (X[r,:] @ W[:,c]) * dinv[r]
__global__ __launch_bounds__(256) void gemm_scale_k(const float* __restrict__ X,
                                                    const float* __restrict__ W,
                                                    const float* __restrict__ dinv,
                                                    float* __restrict__ G, int N) {
    const int lane = threadIdx.x & 63;
    float w[64];
#pragma unroll
    for (int k = 0; k < 64; ++k) w[k] = W[k * 64 + lane];
    const int wid = blockIdx.x * (blockDim.x >> 6) + (threadIdx.x >> 6);
    const int nw = gridDim.x * (blockDim.x >> 6);
    for (int r = wid * 2; r < N; r += nw * 2) {
        const int r1 = r + 1;
        float xa = X[(size_t)r * 64 + lane];
        float xb = (r1 < N) ? X[(size_t)r1 * 64 + lane] : 0.0f;
        float a0 = 0.f, a1 = 0.f, a2 = 0.f, a3 = 0.f;
        float c0 = 0.f, c1 = 0.f, c2 = 0.f, c3 = 0.f;
#pragma unroll
        for (int k = 0; k < 64; k += 4) {
            a0 = fmaf(breadlane(xa, k + 0), w[k + 0], a0);
            a1 = fmaf(breadlane(xa, k + 1), w[k + 1], a1);
            a2 = fmaf(breadlane(xa, k + 2), w[k + 2], a2);
            a3 = fmaf(breadlane(xa, k + 3), w[k + 3], a3);
            c0 = fmaf(breadlane(xb, k + 0), w[k + 0], c0);
            c1 = fmaf(breadlane(xb, k + 1), w[k + 1], c1);
            c2 = fmaf(breadlane(xb, k + 2), w[k + 2], c2);
            c3 = fmaf(breadlane(xb, k + 3), w[k + 3], c3);
        }
        G[(size_t)r * 64 + lane] = (a0 + a1 + a2 + a3) * dinv[r];
        if (r1 < N) G[(size_t)r1 * 64 + lane] = (c0 + c1 + c2 + c3) * dinv[r1];
    }
}

// H[node][:] = relu(dinv[node]*(G[node][:] + sum_src G[src][:]) + b)
// wave = 1 node; 64 lanes fetch 4 source rows per iteration as float4
__global__ __launch_bounds__(256) void agg_k(const float4* __restrict__ G4,
                                             const unsigned int* __restrict__ offs,
                                             const unsigned int* __restrict__ cnt,
                                             const unsigned int* __restrict__ srcs,
                                             const float* __restrict__ dinv,
                                             const float* __restrict__ bias,
                                             float4* __restrict__ H4, int N) {
    const int lane = threadIdx.x & 63;
    const int grp = lane >> 4;   // which of 4 rows in a quad
    const int sub = lane & 15;   // 16 lanes x float4 = one 64-ch row
    const int node = blockIdx.x * (blockDim.x >> 6) + (threadIdx.x >> 6);
    if (node >= N) return;
    const unsigned int o = offs[node];
    const unsigned int c = cnt[node];
    float4 acc = make_float4(0.f, 0.f, 0.f, 0.f);
    unsigned int j = 0;
    for (; j + 4 <= c; j += 4) {
        unsigned int r = srcs[o + j + grp];
        float4 val = G4[(size_t)r * 16 + sub];
        acc.x += val.x; acc.y += val.y; acc.z += val.z; acc.w += val.w;
    }
    if (j + grp < c) {
        unsigned int r = srcs[o + j + grp];
        float4 val = G4[(size_t)r * 16 + sub];
        acc.x += val.x; acc.y += val.y; acc.z += val.z; acc.w += val.w;
    }
#pragma unroll
    for (int m = 16; m <= 32; m <<= 1) {
        acc.x += __shfl_xor(acc.x, m, 64);
        acc.y += __shfl_xor(acc.y, m, 64);
        acc.z += __shfl_xor(acc.z, m, 64);
        acc.w += __shfl_xor(acc.w, m, 64);
    }
    if (grp == 0) {
        float4 g = G4[(size_t)node * 16 + sub];
        const float dv = dinv[node];
        float4 b4 = ((const float4*)bias)[sub];
        float4 out;
        out.x = fmaxf(fmaf(acc.x + g.x, dv, b4.x), 0.0f);
        out.y = fmaxf(fmaf(acc.y + g.y, dv, b4.y), 0.0f);
        out.z = fmaxf(fmaf(acc.z + g.z, dv, b4.z), 0.0f);
        out.w = fmaxf(fmaf(acc.w + g.w, dv, b4.w), 0.0f);
        H4[(size_t)node * 16 + sub] = out;
    }
}

// sorted-batch mean pool: running per-wave accumulator, flush on graph change
__global__ __launch_bounds__(256) void pool_k(const float* __restrict__ H,
                                              const int* __restrict__ batch,
                                              float* __restrict__ pooled,
                                              float* __restrict__ cntg, int N) {
    const int c = threadIdx.x & 63;
    const int sub = threadIdx.x >> 6;
    const int base = blockIdx.x * 256;
    const int end = min(base + 256, N);
    float acc = 0.f, cacc = 0.f;
    int cur = -1;
    for (int i = base + sub; i < end; i += 4) {
        int g = batch[i];
        if (g != cur) {
            if (cur >= 0) {
                atomicAdd(&pooled[cur * 64 + c], acc);
                if (c == 0) atomicAdd(&cntg[cur], cacc);
            }
            cur = g;
            acc = 0.f;
            cacc = 0.f;
        }
        acc += H[(size_t)i * 64 + c];
        cacc += 1.f;
    }
    if (cur >= 0) {
        atomicAdd(&pooled[cur * 64 + c], acc);
        if (c == 0) atomicAdd(&cntg[cur], cacc);
    }
}

__global__ __launch_bounds__(64) void fc_k(const float* __restrict__ pooled,
                                           const float* __restrict__ cntg,
                                           const float* __restrict__ Wfc,
                                           const float* __restrict__ bfc,
                                           float* __restrict__ out) {
    __shared__ float p[64];
    const int g = blockIdx.x;
    const int t = threadIdx.x;
    const float cc = fmaxf(cntg[g], 1.0f);
    p[t] = pooled[g * 64 + t] / cc;
    __syncthreads();
    if (t < 10) {
        float a = bfc[t];
#pragma unroll
        for (int k = 0; k < 64; ++k) a = fmaf(p[k], Wfc[k * 10 + t], a);
        out[g * 10 + t] = a;
    }
}

extern "C" void kernel_launch(void* const* d_in, const int* in_sizes, int n_in,
                              void* d_out, int out_size, void* d_ws, size_t ws_size,
                              hipStream_t stream) {
    const float* x     = (const float*)d_in[0];
    const float* W1    = (const float*)d_in[1];
    const float* b1    = (const float*)d_in[2];
    const float* W2    = (const float*)d_in[3];
    const float* b2    = (const float*)d_in[4];
    const float* Wfc   = (const float*)d_in[5];
    const float* bfc   = (const float*)d_in[6];
    const int*   eidx  = (const int*)d_in[7];
    const int*   batch = (const int*)d_in[8];

    const int N = in_sizes[0] / 64;
    const int E = in_sizes[7] / 2;
    const int* erow = eidx;      // sources
    const int* ecol = eidx + E;  // destinations

    const int nbuck = (N + 511) >> 9;              // coarse buckets (<= 256)
    const int chunk = (E + NBLK_SORT - 1) / NBLK_SORT;

    char* ws = (char*)d_ws;
    size_t off = 0;
    auto alloc = [&](size_t bytes) -> void* {
        void* p = ws + off;
        off = (off + bytes + 511) & ~(size_t)511;
        return p;
    };
    unsigned int* cnt    = (unsigned int*)alloc((size_t)N * 4);
    unsigned int* offs   = (unsigned int*)alloc((size_t)N * 4);
    float*        dinv   = (float*)alloc((size_t)N * 4);
    unsigned int* totals = (unsigned int*)alloc((size_t)nbuck * 4);
    unsigned int* bbase  = (unsigned int*)alloc((size_t)nbuck * 4);
    unsigned int* srcs   = (unsigned int*)alloc((size_t)E * 4);
    float*        G      = (float*)alloc((size_t)N * 64 * 4);
    float*        H      = (float*)alloc((size_t)N * 64 * 4);
    float*        pooled = (float*)alloc((size_t)(128 * 64 + 128) * 4);
    float*        cntg   = pooled + 128 * 64;

    // sort temporaries alias the H region (dead before H is first written)
    unsigned int* packed = (unsigned int*)H;                       // E*4
    unsigned int* bhist  = packed + ((size_t)E + 128);             // NBLK*nbuck*4
    unsigned int* bofs   = bhist + (size_t)NBLK_SORT * nbuck;      // NBLK*nbuck*4

    hipMemsetAsync(pooled, 0, (size_t)(128 * 64 + 128) * 4, stream);

    // --- CSR build: 2-level bucketed counting sort ---
    hist_k<<<NBLK_SORT, 256, 0, stream>>>(ecol, bhist, E, chunk, nbuck);
    scanb_k<<<nbuck, 256, 0, stream>>>(bhist, bofs, totals, nbuck);
    scant_k<<<1, 256, 0, stream>>>(totals, bbase, nbuck);
    scatter_k<<<NBLK_SORT, 256, 0, stream>>>(erow, ecol, bbase, bofs, packed, E, chunk, nbuck);
    fine_k<<<nbuck, 512, 0, stream>>>(packed, bbase, totals, cnt, offs, dinv, srcs, N);

    // --- layer 1 ---
    gemm_scale_k<<<1024, 256, 0, stream>>>(x, W1, dinv, G, N);
    agg_k<<<(N + 3) / 4, 256, 0, stream>>>((const float4*)G, offs, cnt, srcs, dinv, b1,
                                           (float4*)H, N);

    // --- layer 2 ---
    gemm_scale_k<<<1024, 256, 0, stream>>>(H, W2, dinv, G, N);
    agg_k<<<(N + 3) / 4, 256, 0, stream>>>((const float4*)G, offs, cnt, srcs, dinv, b2,
                                           (float4*)H, N);

    // --- pooling + FC ---
    pool_k<<<(N + 255) / 256, 256, 0, stream>>>(H, batch, pooled, cntg, N);
    fc_k<<<128, 64, 0, stream>>>(pooled, cntg, Wfc, bfc, (float*)d_out);
}

// Round 3
// 211.305 us; speedup vs baseline: 1.7545x; 1.1438x over previous
//
#include <hip/hip_runtime.h>
#include <cstdint>

// ---------------------------------------------------------------------------
// GCN forward: 2x (GEMM 64x64 -> symmetric-norm edge aggregation -> bias+ReLU)
// then global mean pool (sorted batch) and 64x10 FC.
//
// CSR build per call via 2-level bucketed counting sort (LDS atomics only).
// Aggregation is gather-based with G stored in bf16 (128 B/row): a wave-load
// covers 8 source rows; out = relu(dinv*(g_self + sum g_src) + b) in f32.
// ---------------------------------------------------------------------------

#define NBLK_SORT 256

static __device__ __forceinline__ float breadlane(float v, int k) {
    return __int_as_float(__builtin_amdgcn_readlane(__float_as_int(v), k));
}

static __device__ __forceinline__ unsigned short f2bf(float f) {
    unsigned int u = __float_as_uint(f);
    u += 0x7FFFu + ((u >> 16) & 1u);  // RNE
    return (unsigned short)(u >> 16);
}
static __device__ __forceinline__ float bflo(unsigned int v) {
    return __uint_as_float(v << 16);
}
static __device__ __forceinline__ float bfhi(unsigned int v) {
    return __uint_as_float(v & 0xFFFF0000u);
}

__global__ __launch_bounds__(256) void hist_k(const int* __restrict__ ecol,
                                              unsigned int* __restrict__ bhist,
                                              int E, int chunk, int nbuck) {
    __shared__ unsigned int lh[256];
    lh[threadIdx.x] = 0u;
    __syncthreads();
    const int s = blockIdx.x * chunk;
    const int e = min(s + chunk, E);
    for (int i = s + threadIdx.x; i < e; i += 256)
        atomicAdd(&lh[((unsigned int)ecol[i]) >> 9], 1u);
    __syncthreads();
    if ((int)threadIdx.x < nbuck)
        bhist[blockIdx.x * nbuck + threadIdx.x] = lh[threadIdx.x];
}

// per-bucket exclusive scan across the NBLK_SORT blocks; totals[k] = column sum
__global__ __launch_bounds__(256) void scanb_k(const unsigned int* __restrict__ bhist,
                                               unsigned int* __restrict__ bofs,
                                               unsigned int* __restrict__ totals, int nbuck) {
    __shared__ unsigned int s[256];
    const int k = blockIdx.x;
    const int t = threadIdx.x;
    unsigned int v = bhist[t * nbuck + k];
    s[t] = v;
    __syncthreads();
    for (int d = 1; d < 256; d <<= 1) {
        unsigned int u = (t >= d) ? s[t - d] : 0u;
        __syncthreads();
        s[t] += u;
        __syncthreads();
    }
    bofs[t * nbuck + k] = s[t] - v;
    if (t == 255) totals[k] = s[255];
}

__global__ __launch_bounds__(256) void scant_k(const unsigned int* __restrict__ totals,
                                               unsigned int* __restrict__ base, int nbuck) {
    __shared__ unsigned int s[256];
    const int t = threadIdx.x;
    unsigned int v = (t < nbuck) ? totals[t] : 0u;
    s[t] = v;
    __syncthreads();
    for (int d = 1; d < 256; d <<= 1) {
        unsigned int u = (t >= d) ? s[t - d] : 0u;
        __syncthreads();
        s[t] += u;
        __syncthreads();
    }
    if (t < nbuck) base[t] = s[t] - v;
}

__global__ __launch_bounds__(256) void scatter_k(const int* __restrict__ erow,
                                                 const int* __restrict__ ecol,
                                                 const unsigned int* __restrict__ base,
                                                 const unsigned int* __restrict__ bofs,
                                                 unsigned int* __restrict__ packed,
                                                 int E, int chunk, int nbuck) {
    __shared__ unsigned int cur[256];
    if ((int)threadIdx.x < nbuck)
        cur[threadIdx.x] = base[threadIdx.x] + bofs[blockIdx.x * nbuck + threadIdx.x];
    __syncthreads();
    const int s = blockIdx.x * chunk;
    const int e = min(s + chunk, E);
    for (int i = s + threadIdx.x; i < e; i += 256) {
        unsigned int d = (unsigned int)ecol[i];
        unsigned int k = d >> 9;
        unsigned int p = atomicAdd(&cur[k], 1u);
        packed[p] = (((unsigned int)erow[i]) << 9) | (d & 511u);
    }
}

// one block per bucket: 512-bin fine sort; emits meta(offs,cnt)/dinv and srcs
__global__ __launch_bounds__(512) void fine_k(const unsigned int* __restrict__ packed,
                                              const unsigned int* __restrict__ base,
                                              const unsigned int* __restrict__ totals,
                                              uint2* __restrict__ meta,
                                              float* __restrict__ dinv,
                                              unsigned int* __restrict__ srcs, int N) {
    __shared__ unsigned int fh[512];
    __shared__ unsigned int sc[512];
    const int k = blockIdx.x;
    const int t = threadIdx.x;
    const unsigned int ebase = base[k];
    const unsigned int ecnt = totals[k];
    fh[t] = 0u;
    __syncthreads();
    for (unsigned int j = t; j < ecnt; j += 512)
        atomicAdd(&fh[packed[ebase + j] & 511u], 1u);
    __syncthreads();
    unsigned int v = fh[t];
    sc[t] = v;
    __syncthreads();
    for (int d = 1; d < 512; d <<= 1) {
        unsigned int u = (t >= d) ? sc[t - d] : 0u;
        __syncthreads();
        sc[t] += u;
        __syncthreads();
    }
    const unsigned int excl = sc[t] - v;
    const int node = (k << 9) + t;
    if (node < N) {
        meta[node] = make_uint2(ebase + excl, v);
        dinv[node] = rsqrtf((float)v + 1.0f);  // +1 self loop
    }
    __syncthreads();
    fh[t] = excl;  // reuse as cursor
    __syncthreads();
    for (unsigned int j = t; j < ecnt; j += 512) {
        unsigned int p = packed[ebase + j];
        unsigned int pos = atomicAdd(&fh[p & 511u], 1u);
        srcs[ebase + pos] = p >> 9;
    }
}

// G16[r][c] = bf16((X[r,:] @ W[:,c]) * dinv[r])
__global__ __launch_bounds__(256) void gemm_scale_k(const float* __restrict__ X,
                                                    const float* __restrict__ W,
                                                    const float* __restrict__ dinv,
                                                    unsigned short* __restrict__ G16, int N) {
    const int lane = threadIdx.x & 63;
    float w[64];
#pragma unroll
    for (int k = 0; k < 64; ++k) w[k] = W[k * 64 + lane];
    const int wid = blockIdx.x * (blockDim.x >> 6) + (threadIdx.x >> 6);
    const int nw = gridDim.x * (blockDim.x >> 6);
    for (int r = wid * 2; r < N; r += nw * 2) {
        const int r1 = r + 1;
        float xa = X[(size_t)r * 64 + lane];
        float xb = (r1 < N) ? X[(size_t)r1 * 64 + lane] : 0.0f;
        float a0 = 0.f, a1 = 0.f, a2 = 0.f, a3 = 0.f;
        float c0 = 0.f, c1 = 0.f, c2 = 0.f, c3 = 0.f;
#pragma unroll
        for (int k = 0; k < 64; k += 4) {
            a0 = fmaf(breadlane(xa, k + 0), w[k + 0], a0);
            a1 = fmaf(breadlane(xa, k + 1), w[k + 1], a1);
            a2 = fmaf(breadlane(xa, k + 2), w[k + 2], a2);
            a3 = fmaf(breadlane(xa, k + 3), w[k + 3], a3);
            c0 = fmaf(breadlane(xb, k + 0), w[k + 0], c0);
            c1 = fmaf(breadlane(xb, k + 1), w[k + 1], c1);
            c2 = fmaf(breadlane(xb, k + 2), w[k + 2], c2);
            c3 = fmaf(breadlane(xb, k + 3), w[k + 3], c3);
        }
        G16[(size_t)r * 64 + lane] = f2bf((a0 + a1 + a2 + a3) * dinv[r]);
        if (r1 < N) G16[(size_t)r1 * 64 + lane] = f2bf((c0 + c1 + c2 + c3) * dinv[r1]);
    }
}

// H[node][:] = relu(dinv[node]*(G[node][:] + sum_src G[src][:]) + b)
// wave = 1 node; 8 lanes per row (uint4 = 8 bf16); 8 rows per wave-load.
__global__ __launch_bounds__(256) void agg_k(const uint4* __restrict__ G4,
                                             const uint2* __restrict__ meta,
                                             const unsigned int* __restrict__ srcs,
                                             const float* __restrict__ dinv,
                                             const float* __restrict__ bias,
                                             float4* __restrict__ H4, int N) {
    const int lane = threadIdx.x & 63;
    const int grp = lane >> 3;  // which of 8 rows per load
    const int sub = lane & 7;   // position within a 128B row
    const int node = blockIdx.x * (blockDim.x >> 6) + (threadIdx.x >> 6);
    if (node >= N) return;
    const uint2 oc = meta[node];
    const unsigned int o = oc.x;
    const unsigned int c = oc.y;
    float a0 = 0.f, a1 = 0.f, a2 = 0.f, a3 = 0.f;
    float a4 = 0.f, a5 = 0.f, a6 = 0.f, a7 = 0.f;
#define ACCUM(v)                                        \
    do {                                                \
        a0 += bflo((v).x); a1 += bfhi((v).x);           \
        a2 += bflo((v).y); a3 += bfhi((v).y);           \
        a4 += bflo((v).z); a5 += bfhi((v).z);           \
        a6 += bflo((v).w); a7 += bfhi((v).w);           \
    } while (0)
    unsigned int j = 0;
    for (; j + 16 <= c; j += 16) {
        unsigned int r0 = srcs[o + j + grp];
        unsigned int r1 = srcs[o + j + 8 + grp];
        uint4 v0 = G4[(size_t)r0 * 8 + sub];
        uint4 v1 = G4[(size_t)r1 * 8 + sub];
        ACCUM(v0);
        ACCUM(v1);
    }
    for (; j + 8 <= c; j += 8) {
        unsigned int r = srcs[o + j + grp];
        uint4 v = G4[(size_t)r * 8 + sub];
        ACCUM(v);
    }
    if (j < c) {
        unsigned int idx = j + grp;
        unsigned int r = srcs[o + (idx < c ? idx : c - 1)];
        uint4 v = G4[(size_t)r * 8 + sub];
        if (idx < c) ACCUM(v);
    }
#pragma unroll
    for (int m = 8; m <= 32; m <<= 1) {
        a0 += __shfl_xor(a0, m, 64);
        a1 += __shfl_xor(a1, m, 64);
        a2 += __shfl_xor(a2, m, 64);
        a3 += __shfl_xor(a3, m, 64);
        a4 += __shfl_xor(a4, m, 64);
        a5 += __shfl_xor(a5, m, 64);
        a6 += __shfl_xor(a6, m, 64);
        a7 += __shfl_xor(a7, m, 64);
    }
    if (grp == 0) {
        uint4 g = G4[(size_t)node * 8 + sub];
        ACCUM(g);  // self loop
        const float dv = dinv[node];
        const float4 b0 = ((const float4*)bias)[sub * 2];
        const float4 b1 = ((const float4*)bias)[sub * 2 + 1];
        float4 o0, o1;
        o0.x = fmaxf(fmaf(a0, dv, b0.x), 0.0f);
        o0.y = fmaxf(fmaf(a1, dv, b0.y), 0.0f);
        o0.z = fmaxf(fmaf(a2, dv, b0.z), 0.0f);
        o0.w = fmaxf(fmaf(a3, dv, b0.w), 0.0f);
        o1.x = fmaxf(fmaf(a4, dv, b1.x), 0.0f);
        o1.y = fmaxf(fmaf(a5, dv, b1.y), 0.0f);
        o1.z = fmaxf(fmaf(a6, dv, b1.z), 0.0f);
        o1.w = fmaxf(fmaf(a7, dv, b1.w), 0.0f);
        H4[(size_t)node * 16 + sub * 2] = o0;
        H4[(size_t)node * 16 + sub * 2 + 1] = o1;
    }
#undef ACCUM
}

// sorted-batch mean pool: running per-wave accumulator, flush on graph change
__global__ __launch_bounds__(256) void pool_k(const float* __restrict__ H,
                                              const int* __restrict__ batch,
                                              float* __restrict__ pooled,
                                              float* __restrict__ cntg, int N) {
    const int c = threadIdx.x & 63;
    const int sub = threadIdx.x >> 6;
    const int base = blockIdx.x * 256;
    const int end = min(base + 256, N);
    float acc = 0.f, cacc = 0.f;
    int cur = -1;
    for (int i = base + sub; i < end; i += 4) {
        int g = batch[i];
        if (g != cur) {
            if (cur >= 0) {
                atomicAdd(&pooled[cur * 64 + c], acc);
                if (c == 0) atomicAdd(&cntg[cur], cacc);
            }
            cur = g;
            acc = 0.f;
            cacc = 0.f;
        }
        acc += H[(size_t)i * 64 + c];
        cacc += 1.f;
    }
    if (cur >= 0) {
        atomicAdd(&pooled[cur * 64 + c], acc);
        if (c == 0) atomicAdd(&cntg[cur], cacc);
    }
}

__global__ __launch_bounds__(64) void fc_k(const float* __restrict__ pooled,
                                           const float* __restrict__ cntg,
                                           const float* __restrict__ Wfc,
                                           const float* __restrict__ bfc,
                                           float* __restrict__ out) {
    __shared__ float p[64];
    const int g = blockIdx.x;
    const int t = threadIdx.x;
    const float cc = fmaxf(cntg[g], 1.0f);
    p[t] = pooled[g * 64 + t] / cc;
    __syncthreads();
    if (t < 10) {
        float a = bfc[t];
#pragma unroll
        for (int k = 0; k < 64; ++k) a = fmaf(p[k], Wfc[k * 10 + t], a);
        out[g * 10 + t] = a;
    }
}

extern "C" void kernel_launch(void* const* d_in, const int* in_sizes, int n_in,
                              void* d_out, int out_size, void* d_ws, size_t ws_size,
                              hipStream_t stream) {
    const float* x     = (const float*)d_in[0];
    const float* W1    = (const float*)d_in[1];
    const float* b1    = (const float*)d_in[2];
    const float* W2    = (const float*)d_in[3];
    const float* b2    = (const float*)d_in[4];
    const float* Wfc   = (const float*)d_in[5];
    const float* bfc   = (const float*)d_in[6];
    const int*   eidx  = (const int*)d_in[7];
    const int*   batch = (const int*)d_in[8];

    const int N = in_sizes[0] / 64;
    const int E = in_sizes[7] / 2;
    const int* erow = eidx;      // sources
    const int* ecol = eidx + E;  // destinations

    const int nbuck = (N + 511) >> 9;  // coarse buckets (<= 256)
    const int chunk = (E + NBLK_SORT - 1) / NBLK_SORT;

    char* ws = (char*)d_ws;
    size_t off = 0;
    auto alloc = [&](size_t bytes) -> void* {
        void* p = ws + off;
        off = (off + bytes + 511) & ~(size_t)511;
        return p;
    };
    uint2*        meta   = (uint2*)alloc((size_t)N * 8);
    float*        dinv   = (float*)alloc((size_t)N * 4);
    unsigned int* totals = (unsigned int*)alloc((size_t)nbuck * 4);
    unsigned int* bbase  = (unsigned int*)alloc((size_t)nbuck * 4);
    unsigned int* srcs   = (unsigned int*)alloc((size_t)E * 4);
    unsigned short* G16  = (unsigned short*)alloc((size_t)N * 64 * 2);
    float*        H      = (float*)alloc((size_t)N * 64 * 4);
    float*        pooled = (float*)alloc((size_t)(128 * 64 + 128) * 4);
    float*        cntg   = pooled + 128 * 64;

    // sort temporaries alias the H region (dead before H is first written)
    unsigned int* packed = (unsigned int*)H;                   // E*4
    unsigned int* bhist  = packed + ((size_t)E + 128);         // NBLK*nbuck*4
    unsigned int* bofs   = bhist + (size_t)NBLK_SORT * nbuck;  // NBLK*nbuck*4

    hipMemsetAsync(pooled, 0, (size_t)(128 * 64 + 128) * 4, stream);

    // --- CSR build: 2-level bucketed counting sort ---
    hist_k<<<NBLK_SORT, 256, 0, stream>>>(ecol, bhist, E, chunk, nbuck);
    scanb_k<<<nbuck, 256, 0, stream>>>(bhist, bofs, totals, nbuck);
    scant_k<<<1, 256, 0, stream>>>(totals, bbase, nbuck);
    scatter_k<<<NBLK_SORT, 256, 0, stream>>>(erow, ecol, bbase, bofs, packed, E, chunk, nbuck);
    fine_k<<<nbuck, 512, 0, stream>>>(packed, bbase, totals, meta, dinv, srcs, N);

    // --- layer 1 ---
    gemm_scale_k<<<1024, 256, 0, stream>>>(x, W1, dinv, G16, N);
    agg_k<<<(N + 3) / 4, 256, 0, stream>>>((const uint4*)G16, meta, srcs, dinv, b1,
                                           (float4*)H, N);

    // --- layer 2 ---
    gemm_scale_k<<<1024, 256, 0, stream>>>(H, W2, dinv, G16, N);
    agg_k<<<(N + 3) / 4, 256, 0, stream>>>((const uint4*)G16, meta, srcs, dinv, b2,
                                           (float4*)H, N);

    // --- pooling + FC ---
    pool_k<<<(N + 255) / 256, 256, 0, stream>>>(H, batch, pooled, cntg, N);
    fc_k<<<128, 64, 0, stream>>>(pooled, cntg, Wfc, bfc, (float*)d_out);
}

// Round 4
// 186.140 us; speedup vs baseline: 1.9917x; 1.1352x over previous
//
#include <hip/hip_runtime.h>
#include <cstdint>

// ---------------------------------------------------------------------------
// GCN forward: 2x (GEMM 64x64 -> symmetric-norm edge aggregation -> bias+ReLU)
// then global mean pool (sorted batch) and 64x10 FC.
//
// CSR build per call via 2-level bucketed counting sort (LDS atomics only).
// Aggregation: wave = 8 nodes, 8 lanes/node, lane owns 8 channels -> no
// cross-lane reduction. G and H stored bf16 (128 B/row).
// ---------------------------------------------------------------------------

#define NBLK_SORT 256

static __device__ __forceinline__ float breadlane(float v, int k) {
    return __int_as_float(__builtin_amdgcn_readlane(__float_as_int(v), k));
}

static __device__ __forceinline__ unsigned int f2bf_r(float f) {
    unsigned int u = __float_as_uint(f);
    return u + 0x7FFFu + ((u >> 16) & 1u);  // rounded, needs >>16
}
static __device__ __forceinline__ float bflo(unsigned int v) {
    return __uint_as_float(v << 16);
}
static __device__ __forceinline__ float bfhi(unsigned int v) {
    return __uint_as_float(v & 0xFFFF0000u);
}

__global__ __launch_bounds__(256) void hist_k(const int* __restrict__ ecol,
                                              unsigned int* __restrict__ bhist,
                                              int E, int chunk, int nbuck) {
    __shared__ unsigned int lh[256];
    lh[threadIdx.x] = 0u;
    __syncthreads();
    const int s = blockIdx.x * chunk;
    const int e = min(s + chunk, E);
    for (int i = s + threadIdx.x; i < e; i += 256)
        atomicAdd(&lh[((unsigned int)ecol[i]) >> 9], 1u);
    __syncthreads();
    if ((int)threadIdx.x < nbuck)
        bhist[blockIdx.x * nbuck + threadIdx.x] = lh[threadIdx.x];
}

// per-bucket exclusive scan across the NBLK_SORT blocks; totals[k] = column sum
__global__ __launch_bounds__(256) void scanb_k(const unsigned int* __restrict__ bhist,
                                               unsigned int* __restrict__ bofs,
                                               unsigned int* __restrict__ totals, int nbuck) {
    __shared__ unsigned int s[256];
    const int k = blockIdx.x;
    const int t = threadIdx.x;
    unsigned int v = bhist[t * nbuck + k];
    s[t] = v;
    __syncthreads();
    for (int d = 1; d < 256; d <<= 1) {
        unsigned int u = (t >= d) ? s[t - d] : 0u;
        __syncthreads();
        s[t] += u;
        __syncthreads();
    }
    bofs[t * nbuck + k] = s[t] - v;
    if (t == 255) totals[k] = s[255];
}

__global__ __launch_bounds__(256) void scant_k(const unsigned int* __restrict__ totals,
                                               unsigned int* __restrict__ base, int nbuck) {
    __shared__ unsigned int s[256];
    const int t = threadIdx.x;
    unsigned int v = (t < nbuck) ? totals[t] : 0u;
    s[t] = v;
    __syncthreads();
    for (int d = 1; d < 256; d <<= 1) {
        unsigned int u = (t >= d) ? s[t - d] : 0u;
        __syncthreads();
        s[t] += u;
        __syncthreads();
    }
    if (t < nbuck) base[t] = s[t] - v;
}

__global__ __launch_bounds__(256) void scatter_k(const int* __restrict__ erow,
                                                 const int* __restrict__ ecol,
                                                 const unsigned int* __restrict__ base,
                                                 const unsigned int* __restrict__ bofs,
                                                 unsigned int* __restrict__ packed,
                                                 int E, int chunk, int nbuck) {
    __shared__ unsigned int cur[256];
    if ((int)threadIdx.x < nbuck)
        cur[threadIdx.x] = base[threadIdx.x] + bofs[blockIdx.x * nbuck + threadIdx.x];
    __syncthreads();
    const int s = blockIdx.x * chunk;
    const int e = min(s + chunk, E);
    for (int i = s + threadIdx.x; i < e; i += 256) {
        unsigned int d = (unsigned int)ecol[i];
        unsigned int k = d >> 9;
        unsigned int p = atomicAdd(&cur[k], 1u);
        packed[p] = (((unsigned int)erow[i]) << 9) | (d & 511u);
    }
}

// one block per bucket: 512-bin fine sort; emits meta(offs,cnt)/dinv and srcs
__global__ __launch_bounds__(512) void fine_k(const unsigned int* __restrict__ packed,
                                              const unsigned int* __restrict__ base,
                                              const unsigned int* __restrict__ totals,
                                              uint2* __restrict__ meta,
                                              float* __restrict__ dinv,
                                              unsigned int* __restrict__ srcs, int N) {
    __shared__ unsigned int fh[512];
    __shared__ unsigned int sc[512];
    const int k = blockIdx.x;
    const int t = threadIdx.x;
    const unsigned int ebase = base[k];
    const unsigned int ecnt = totals[k];
    fh[t] = 0u;
    __syncthreads();
    for (unsigned int j = t; j < ecnt; j += 512)
        atomicAdd(&fh[packed[ebase + j] & 511u], 1u);
    __syncthreads();
    unsigned int v = fh[t];
    sc[t] = v;
    __syncthreads();
    for (int d = 1; d < 512; d <<= 1) {
        unsigned int u = (t >= d) ? sc[t - d] : 0u;
        __syncthreads();
        sc[t] += u;
        __syncthreads();
    }
    const unsigned int excl = sc[t] - v;
    const int node = (k << 9) + t;
    if (node < N) {
        meta[node] = make_uint2(ebase + excl, v);
        dinv[node] = rsqrtf((float)v + 1.0f);  // +1 self loop
    }
    __syncthreads();
    fh[t] = excl;  // reuse as cursor
    __syncthreads();
    for (unsigned int j = t; j < ecnt; j += 512) {
        unsigned int p = packed[ebase + j];
        unsigned int pos = atomicAdd(&fh[p & 511u], 1u);
        srcs[ebase + pos] = p >> 9;
    }
}

// G16[r][c] = bf16((X[r,:] @ W[:,c]) * dinv[r]); input f32 or bf16
template <bool BF16IN>
__global__ __launch_bounds__(256) void gemm_scale_k(const void* __restrict__ Xv,
                                                    const float* __restrict__ W,
                                                    const float* __restrict__ dinv,
                                                    unsigned short* __restrict__ G16, int N) {
    const int lane = threadIdx.x & 63;
    float w[64];
#pragma unroll
    for (int k = 0; k < 64; ++k) w[k] = W[k * 64 + lane];
    const int wid = blockIdx.x * (blockDim.x >> 6) + (threadIdx.x >> 6);
    const int nw = gridDim.x * (blockDim.x >> 6);
    for (int r = wid * 2; r < N; r += nw * 2) {
        const int r1 = r + 1;
        float xa, xb;
        if (BF16IN) {
            const unsigned short* X = (const unsigned short*)Xv;
            xa = bflo((unsigned int)X[(size_t)r * 64 + lane]);
            xb = (r1 < N) ? bflo((unsigned int)X[(size_t)r1 * 64 + lane]) : 0.0f;
        } else {
            const float* X = (const float*)Xv;
            xa = X[(size_t)r * 64 + lane];
            xb = (r1 < N) ? X[(size_t)r1 * 64 + lane] : 0.0f;
        }
        float a0 = 0.f, a1 = 0.f, a2 = 0.f, a3 = 0.f;
        float c0 = 0.f, c1 = 0.f, c2 = 0.f, c3 = 0.f;
#pragma unroll
        for (int k = 0; k < 64; k += 4) {
            a0 = fmaf(breadlane(xa, k + 0), w[k + 0], a0);
            a1 = fmaf(breadlane(xa, k + 1), w[k + 1], a1);
            a2 = fmaf(breadlane(xa, k + 2), w[k + 2], a2);
            a3 = fmaf(breadlane(xa, k + 3), w[k + 3], a3);
            c0 = fmaf(breadlane(xb, k + 0), w[k + 0], c0);
            c1 = fmaf(breadlane(xb, k + 1), w[k + 1], c1);
            c2 = fmaf(breadlane(xb, k + 2), w[k + 2], c2);
            c3 = fmaf(breadlane(xb, k + 3), w[k + 3], c3);
        }
        G16[(size_t)r * 64 + lane] = (unsigned short)(f2bf_r((a0 + a1 + a2 + a3) * dinv[r]) >> 16);
        if (r1 < N)
            G16[(size_t)r1 * 64 + lane] = (unsigned short)(f2bf_r((c0 + c1 + c2 + c3) * dinv[r1]) >> 16);
    }
}

// H[node][:] = relu(dinv[node]*(G[node][:] + sum_src G[src][:]) + b)  (bf16 out)
// wave = 8 nodes; 8 lanes/node; lane owns 8 channels -> no cross-lane reduce.
__global__ __launch_bounds__(256) void agg_k(const char* __restrict__ Gb,
                                             const uint2* __restrict__ meta,
                                             const unsigned int* __restrict__ srcs,
                                             const float* __restrict__ dinv,
                                             const float* __restrict__ bias,
                                             uint4* __restrict__ H4, int N) {
    const int lane = threadIdx.x & 63;
    const int grp = lane >> 3;  // node slot within wave
    const int sub = lane & 7;   // uint4 index within the 128B row
    const int wid = blockIdx.x * (blockDim.x >> 6) + (threadIdx.x >> 6);
    const int node = wid * 8 + grp;
    if (node >= N) return;
    const uint2 oc = meta[node];
    const unsigned int o = oc.x;
    const unsigned int c = oc.y;
    const unsigned int suboff = (unsigned int)sub << 4;
    float a0 = 0.f, a1 = 0.f, a2 = 0.f, a3 = 0.f;
    float a4 = 0.f, a5 = 0.f, a6 = 0.f, a7 = 0.f;
#define ACCUM(v)                              \
    do {                                      \
        a0 += bflo((v).x); a1 += bfhi((v).x); \
        a2 += bflo((v).y); a3 += bfhi((v).y); \
        a4 += bflo((v).z); a5 += bfhi((v).z); \
        a6 += bflo((v).w); a7 += bfhi((v).w); \
    } while (0)
    unsigned int j = 0;
    for (; j + 2 <= c; j += 2) {
        unsigned int r0 = srcs[o + j];
        unsigned int r1 = srcs[o + j + 1];
        uint4 v0 = *(const uint4*)(Gb + ((r0 << 7) | suboff));
        uint4 v1 = *(const uint4*)(Gb + ((r1 << 7) | suboff));
        ACCUM(v0);
        ACCUM(v1);
    }
    if (j < c) {
        unsigned int r = srcs[o + j];
        uint4 v = *(const uint4*)(Gb + ((r << 7) | suboff));
        ACCUM(v);
    }
    {   // self loop
        uint4 g = *(const uint4*)(Gb + (((unsigned int)node << 7) | suboff));
        ACCUM(g);
    }
#undef ACCUM
    const float dv = dinv[node];
    const float4 b0 = ((const float4*)bias)[sub * 2];
    const float4 b1 = ((const float4*)bias)[sub * 2 + 1];
    float o0 = fmaxf(fmaf(a0, dv, b0.x), 0.0f);
    float o1 = fmaxf(fmaf(a1, dv, b0.y), 0.0f);
    float o2 = fmaxf(fmaf(a2, dv, b0.z), 0.0f);
    float o3 = fmaxf(fmaf(a3, dv, b0.w), 0.0f);
    float o4 = fmaxf(fmaf(a4, dv, b1.x), 0.0f);
    float o5 = fmaxf(fmaf(a5, dv, b1.y), 0.0f);
    float o6 = fmaxf(fmaf(a6, dv, b1.z), 0.0f);
    float o7 = fmaxf(fmaf(a7, dv, b1.w), 0.0f);
    uint4 out;
    out.x = (f2bf_r(o0) >> 16) | (f2bf_r(o1) & 0xFFFF0000u);
    out.y = (f2bf_r(o2) >> 16) | (f2bf_r(o3) & 0xFFFF0000u);
    out.z = (f2bf_r(o4) >> 16) | (f2bf_r(o5) & 0xFFFF0000u);
    out.w = (f2bf_r(o6) >> 16) | (f2bf_r(o7) & 0xFFFF0000u);
    H4[(size_t)node * 8 + sub] = out;
}

// sorted-batch mean pool over bf16 H
__global__ __launch_bounds__(256) void pool_k(const unsigned short* __restrict__ H,
                                              const int* __restrict__ batch,
                                              float* __restrict__ pooled,
                                              float* __restrict__ cntg, int N) {
    const int c = threadIdx.x & 63;
    const int sub = threadIdx.x >> 6;
    const int base = blockIdx.x * 256;
    const int end = min(base + 256, N);
    float acc = 0.f, cacc = 0.f;
    int cur = -1;
    for (int i = base + sub; i < end; i += 4) {
        int g = batch[i];
        if (g != cur) {
            if (cur >= 0) {
                atomicAdd(&pooled[cur * 64 + c], acc);
                if (c == 0) atomicAdd(&cntg[cur], cacc);
            }
            cur = g;
            acc = 0.f;
            cacc = 0.f;
        }
        acc += bflo((unsigned int)H[(size_t)i * 64 + c]);
        cacc += 1.f;
    }
    if (cur >= 0) {
        atomicAdd(&pooled[cur * 64 + c], acc);
        if (c == 0) atomicAdd(&cntg[cur], cacc);
    }
}

__global__ __launch_bounds__(64) void fc_k(const float* __restrict__ pooled,
                                           const float* __restrict__ cntg,
                                           const float* __restrict__ Wfc,
                                           const float* __restrict__ bfc,
                                           float* __restrict__ out) {
    __shared__ float p[64];
    const int g = blockIdx.x;
    const int t = threadIdx.x;
    const float cc = fmaxf(cntg[g], 1.0f);
    p[t] = pooled[g * 64 + t] / cc;
    __syncthreads();
    if (t < 10) {
        float a = bfc[t];
#pragma unroll
        for (int k = 0; k < 64; ++k) a = fmaf(p[k], Wfc[k * 10 + t], a);
        out[g * 10 + t] = a;
    }
}

extern "C" void kernel_launch(void* const* d_in, const int* in_sizes, int n_in,
                              void* d_out, int out_size, void* d_ws, size_t ws_size,
                              hipStream_t stream) {
    const float* x     = (const float*)d_in[0];
    const float* W1    = (const float*)d_in[1];
    const float* b1    = (const float*)d_in[2];
    const float* W2    = (const float*)d_in[3];
    const float* b2    = (const float*)d_in[4];
    const float* Wfc   = (const float*)d_in[5];
    const float* bfc   = (const float*)d_in[6];
    const int*   eidx  = (const int*)d_in[7];
    const int*   batch = (const int*)d_in[8];

    const int N = in_sizes[0] / 64;
    const int E = in_sizes[7] / 2;
    const int* erow = eidx;      // sources
    const int* ecol = eidx + E;  // destinations

    const int nbuck = (N + 511) >> 9;  // coarse buckets (<= 256)
    const int chunk = (E + NBLK_SORT - 1) / NBLK_SORT;

    char* ws = (char*)d_ws;
    size_t off = 0;
    auto alloc = [&](size_t bytes) -> void* {
        void* p = ws + off;
        off = (off + bytes + 511) & ~(size_t)511;
        return p;
    };
    uint2*        meta   = (uint2*)alloc((size_t)N * 8);
    float*        dinv   = (float*)alloc((size_t)N * 4);
    unsigned int* totals = (unsigned int*)alloc((size_t)nbuck * 4);
    unsigned int* bbase  = (unsigned int*)alloc((size_t)nbuck * 4);
    unsigned int* srcs   = (unsigned int*)alloc((size_t)E * 4);
    unsigned short* G16  = (unsigned short*)alloc((size_t)N * 64 * 2);
    unsigned short* H16  = (unsigned short*)alloc((size_t)N * 64 * 2);
    float*        pooled = (float*)alloc((size_t)(128 * 64 + 128) * 4);
    float*        cntg   = pooled + 128 * 64;

    // sort temporaries alias the H region (dead before H is first written)
    unsigned int* packed = (unsigned int*)H16;                 // E*4 (needs E*4 <= N*128)
    unsigned int* bhist  = (unsigned int*)alloc((size_t)NBLK_SORT * nbuck * 4);
    unsigned int* bofs   = (unsigned int*)alloc((size_t)NBLK_SORT * nbuck * 4);

    hipMemsetAsync(pooled, 0, (size_t)(128 * 64 + 128) * 4, stream);

    // --- CSR build: 2-level bucketed counting sort ---
    hist_k<<<NBLK_SORT, 256, 0, stream>>>(ecol, bhist, E, chunk, nbuck);
    scanb_k<<<nbuck, 256, 0, stream>>>(bhist, bofs, totals, nbuck);
    scant_k<<<1, 256, 0, stream>>>(totals, bbase, nbuck);
    scatter_k<<<NBLK_SORT, 256, 0, stream>>>(erow, ecol, bbase, bofs, packed, E, chunk, nbuck);
    fine_k<<<nbuck, 512, 0, stream>>>(packed, bbase, totals, meta, dinv, srcs, N);

    const int aggB = (N + 31) / 32;  // 4 waves/block x 8 nodes/wave

    // --- layer 1 ---
    gemm_scale_k<false><<<1024, 256, 0, stream>>>(x, W1, dinv, G16, N);
    agg_k<<<aggB, 256, 0, stream>>>((const char*)G16, meta, srcs, dinv, b1, (uint4*)H16, N);

    // --- layer 2 ---
    gemm_scale_k<true><<<1024, 256, 0, stream>>>(H16, W2, dinv, G16, N);
    agg_k<<<aggB, 256, 0, stream>>>((const char*)G16, meta, srcs, dinv, b2, (uint4*)H16, N);

    // --- pooling + FC ---
    pool_k<<<(N + 255) / 256, 256, 0, stream>>>(H16, batch, pooled, cntg, N);
    fc_k<<<128, 64, 0, stream>>>(pooled, cntg, Wfc, bfc, (float*)d_out);
}

// Round 5
// 180.830 us; speedup vs baseline: 2.0502x; 1.0294x over previous
//
#include <hip/hip_runtime.h>
#include <cstdint>

// ---------------------------------------------------------------------------
// GCN forward: 2x (GEMM 64x64 -> symmetric-norm edge aggregation -> bias+ReLU)
// then global mean pool (sorted batch) and 64x10 FC.
//
// CSR build per call via 2-level bucketed counting sort (LDS atomics only).
// Aggregation: wave = 8 nodes, 8 lanes/node, lane owns 8 channels -> no
// cross-lane reduction. G and H stored bf16 (128 B/row).
// pooled/cntg zeroed inside hist_k (hipMemsetAsync in-graph cost ~43 us).
// ---------------------------------------------------------------------------

#define NBLK_SORT 256

static __device__ __forceinline__ float breadlane(float v, int k) {
    return __int_as_float(__builtin_amdgcn_readlane(__float_as_int(v), k));
}

static __device__ __forceinline__ unsigned int f2bf_r(float f) {
    unsigned int u = __float_as_uint(f);
    return u + 0x7FFFu + ((u >> 16) & 1u);  // rounded, needs >>16
}
static __device__ __forceinline__ float bflo(unsigned int v) {
    return __uint_as_float(v << 16);
}
static __device__ __forceinline__ float bfhi(unsigned int v) {
    return __uint_as_float(v & 0xFFFF0000u);
}

__global__ __launch_bounds__(256) void hist_k(const int* __restrict__ ecol,
                                              unsigned int* __restrict__ bhist,
                                              float* __restrict__ pooled_zero, int zn,
                                              int E, int chunk, int nbuck) {
    __shared__ unsigned int lh[256];
    lh[threadIdx.x] = 0u;
    __syncthreads();
    if (blockIdx.x == 0) {  // zero pooled+cntg (replaces in-graph memset)
        for (int i = threadIdx.x; i < zn; i += 256) pooled_zero[i] = 0.f;
    }
    const int s = blockIdx.x * chunk;
    const int e = min(s + chunk, E);
    for (int i = s + threadIdx.x; i < e; i += 256)
        atomicAdd(&lh[((unsigned int)ecol[i]) >> 9], 1u);
    __syncthreads();
    if ((int)threadIdx.x < nbuck)
        bhist[blockIdx.x * nbuck + threadIdx.x] = lh[threadIdx.x];
}

// per-bucket exclusive scan across the NBLK_SORT blocks; totals[k] = column sum
__global__ __launch_bounds__(256) void scanb_k(const unsigned int* __restrict__ bhist,
                                               unsigned int* __restrict__ bofs,
                                               unsigned int* __restrict__ totals, int nbuck) {
    __shared__ unsigned int s[256];
    const int k = blockIdx.x;
    const int t = threadIdx.x;
    unsigned int v = bhist[t * nbuck + k];
    s[t] = v;
    __syncthreads();
    for (int d = 1; d < 256; d <<= 1) {
        unsigned int u = (t >= d) ? s[t - d] : 0u;
        __syncthreads();
        s[t] += u;
        __syncthreads();
    }
    bofs[t * nbuck + k] = s[t] - v;
    if (t == 255) totals[k] = s[255];
}

__global__ __launch_bounds__(256) void scant_k(const unsigned int* __restrict__ totals,
                                               unsigned int* __restrict__ base, int nbuck) {
    __shared__ unsigned int s[256];
    const int t = threadIdx.x;
    unsigned int v = (t < nbuck) ? totals[t] : 0u;
    s[t] = v;
    __syncthreads();
    for (int d = 1; d < 256; d <<= 1) {
        unsigned int u = (t >= d) ? s[t - d] : 0u;
        __syncthreads();
        s[t] += u;
        __syncthreads();
    }
    if (t < nbuck) base[t] = s[t] - v;
}

__global__ __launch_bounds__(256) void scatter_k(const int* __restrict__ erow,
                                                 const int* __restrict__ ecol,
                                                 const unsigned int* __restrict__ base,
                                                 const unsigned int* __restrict__ bofs,
                                                 unsigned int* __restrict__ packed,
                                                 int E, int chunk, int nbuck) {
    __shared__ unsigned int cur[256];
    if ((int)threadIdx.x < nbuck)
        cur[threadIdx.x] = base[threadIdx.x] + bofs[blockIdx.x * nbuck + threadIdx.x];
    __syncthreads();
    const int s = blockIdx.x * chunk;
    const int e = min(s + chunk, E);
    for (int i = s + threadIdx.x; i < e; i += 256) {
        unsigned int d = (unsigned int)ecol[i];
        unsigned int k = d >> 9;
        unsigned int p = atomicAdd(&cur[k], 1u);
        packed[p] = (((unsigned int)erow[i]) << 9) | (d & 511u);
    }
}

// one block per bucket: 512-bin fine sort; emits meta(offs,cnt)/dinv and srcs
__global__ __launch_bounds__(512) void fine_k(const unsigned int* __restrict__ packed,
                                              const unsigned int* __restrict__ base,
                                              const unsigned int* __restrict__ totals,
                                              uint2* __restrict__ meta,
                                              float* __restrict__ dinv,
                                              unsigned int* __restrict__ srcs, int N) {
    __shared__ unsigned int fh[512];
    __shared__ unsigned int sc[512];
    const int k = blockIdx.x;
    const int t = threadIdx.x;
    const unsigned int ebase = base[k];
    const unsigned int ecnt = totals[k];
    fh[t] = 0u;
    __syncthreads();
    for (unsigned int j = t; j < ecnt; j += 512)
        atomicAdd(&fh[packed[ebase + j] & 511u], 1u);
    __syncthreads();
    unsigned int v = fh[t];
    sc[t] = v;
    __syncthreads();
    for (int d = 1; d < 512; d <<= 1) {
        unsigned int u = (t >= d) ? sc[t - d] : 0u;
        __syncthreads();
        sc[t] += u;
        __syncthreads();
    }
    const unsigned int excl = sc[t] - v;
    const int node = (k << 9) + t;
    if (node < N) {
        meta[node] = make_uint2(ebase + excl, v);
        dinv[node] = rsqrtf((float)v + 1.0f);  // +1 self loop
    }
    __syncthreads();
    fh[t] = excl;  // reuse as cursor
    __syncthreads();
    for (unsigned int j = t; j < ecnt; j += 512) {
        unsigned int p = packed[ebase + j];
        unsigned int pos = atomicAdd(&fh[p & 511u], 1u);
        srcs[ebase + pos] = p >> 9;
    }
}

// G16[r][c] = bf16((X[r,:] @ W[:,c]) * dinv[r]); input f32 or bf16
template <bool BF16IN>
__global__ __launch_bounds__(256) void gemm_scale_k(const void* __restrict__ Xv,
                                                    const float* __restrict__ W,
                                                    const float* __restrict__ dinv,
                                                    unsigned short* __restrict__ G16, int N) {
    const int lane = threadIdx.x & 63;
    float w[64];
#pragma unroll
    for (int k = 0; k < 64; ++k) w[k] = W[k * 64 + lane];
    const int wid = blockIdx.x * (blockDim.x >> 6) + (threadIdx.x >> 6);
    const int nw = gridDim.x * (blockDim.x >> 6);
    for (int r = wid * 2; r < N; r += nw * 2) {
        const int r1 = r + 1;
        float xa, xb;
        if (BF16IN) {
            const unsigned short* X = (const unsigned short*)Xv;
            xa = bflo((unsigned int)X[(size_t)r * 64 + lane]);
            xb = (r1 < N) ? bflo((unsigned int)X[(size_t)r1 * 64 + lane]) : 0.0f;
        } else {
            const float* X = (const float*)Xv;
            xa = X[(size_t)r * 64 + lane];
            xb = (r1 < N) ? X[(size_t)r1 * 64 + lane] : 0.0f;
        }
        float a0 = 0.f, a1 = 0.f, a2 = 0.f, a3 = 0.f;
        float c0 = 0.f, c1 = 0.f, c2 = 0.f, c3 = 0.f;
#pragma unroll
        for (int k = 0; k < 64; k += 4) {
            a0 = fmaf(breadlane(xa, k + 0), w[k + 0], a0);
            a1 = fmaf(breadlane(xa, k + 1), w[k + 1], a1);
            a2 = fmaf(breadlane(xa, k + 2), w[k + 2], a2);
            a3 = fmaf(breadlane(xa, k + 3), w[k + 3], a3);
            c0 = fmaf(breadlane(xb, k + 0), w[k + 0], c0);
            c1 = fmaf(breadlane(xb, k + 1), w[k + 1], c1);
            c2 = fmaf(breadlane(xb, k + 2), w[k + 2], c2);
            c3 = fmaf(breadlane(xb, k + 3), w[k + 3], c3);
        }
        G16[(size_t)r * 64 + lane] = (unsigned short)(f2bf_r((a0 + a1 + a2 + a3) * dinv[r]) >> 16);
        if (r1 < N)
            G16[(size_t)r1 * 64 + lane] = (unsigned short)(f2bf_r((c0 + c1 + c2 + c3) * dinv[r1]) >> 16);
    }
}

// H[node][:] = relu(dinv[node]*(G[node][:] + sum_src G[src][:]) + b)  (bf16 out)
// wave = 8 nodes; 8 lanes/node; lane owns 8 channels -> no cross-lane reduce.
__global__ __launch_bounds__(256) void agg_k(const char* __restrict__ Gb,
                                             const uint2* __restrict__ meta,
                                             const unsigned int* __restrict__ srcs,
                                             const float* __restrict__ dinv,
                                             const float* __restrict__ bias,
                                             uint4* __restrict__ H4, int N) {
    const int lane = threadIdx.x & 63;
    const int grp = lane >> 3;  // node slot within wave
    const int sub = lane & 7;   // uint4 index within the 128B row
    const int wid = blockIdx.x * (blockDim.x >> 6) + (threadIdx.x >> 6);
    const int node = wid * 8 + grp;
    if (node >= N) return;
    const uint2 oc = meta[node];
    const unsigned int o = oc.x;
    const unsigned int c = oc.y;
    const unsigned int suboff = (unsigned int)sub << 4;
    float a0 = 0.f, a1 = 0.f, a2 = 0.f, a3 = 0.f;
    float a4 = 0.f, a5 = 0.f, a6 = 0.f, a7 = 0.f;
#define ACCUM(v)                              \
    do {                                      \
        a0 += bflo((v).x); a1 += bfhi((v).x); \
        a2 += bflo((v).y); a3 += bfhi((v).y); \
        a4 += bflo((v).z); a5 += bfhi((v).z); \
        a6 += bflo((v).w); a7 += bfhi((v).w); \
    } while (0)
    unsigned int j = 0;
    for (; j + 2 <= c; j += 2) {
        unsigned int r0 = srcs[o + j];
        unsigned int r1 = srcs[o + j + 1];
        uint4 v0 = *(const uint4*)(Gb + ((r0 << 7) | suboff));
        uint4 v1 = *(const uint4*)(Gb + ((r1 << 7) | suboff));
        ACCUM(v0);
        ACCUM(v1);
    }
    if (j < c) {
        unsigned int r = srcs[o + j];
        uint4 v = *(const uint4*)(Gb + ((r << 7) | suboff));
        ACCUM(v);
    }
    {   // self loop
        uint4 g = *(const uint4*)(Gb + (((unsigned int)node << 7) | suboff));
        ACCUM(g);
    }
#undef ACCUM
    const float dv = dinv[node];
    const float4 b0 = ((const float4*)bias)[sub * 2];
    const float4 b1 = ((const float4*)bias)[sub * 2 + 1];
    float o0 = fmaxf(fmaf(a0, dv, b0.x), 0.0f);
    float o1 = fmaxf(fmaf(a1, dv, b0.y), 0.0f);
    float o2 = fmaxf(fmaf(a2, dv, b0.z), 0.0f);
    float o3 = fmaxf(fmaf(a3, dv, b0.w), 0.0f);
    float o4 = fmaxf(fmaf(a4, dv, b1.x), 0.0f);
    float o5 = fmaxf(fmaf(a5, dv, b1.y), 0.0f);
    float o6 = fmaxf(fmaf(a6, dv, b1.z), 0.0f);
    float o7 = fmaxf(fmaf(a7, dv, b1.w), 0.0f);
    uint4 out;
    out.x = (f2bf_r(o0) >> 16) | (f2bf_r(o1) & 0xFFFF0000u);
    out.y = (f2bf_r(o2) >> 16) | (f2bf_r(o3) & 0xFFFF0000u);
    out.z = (f2bf_r(o4) >> 16) | (f2bf_r(o5) & 0xFFFF0000u);
    out.w = (f2bf_r(o6) >> 16) | (f2bf_r(o7) & 0xFFFF0000u);
    H4[(size_t)node * 8 + sub] = out;
}

// sorted-batch mean pool over bf16 H; lane owns 2 channels via uint loads
__global__ __launch_bounds__(256) void pool_k(const unsigned int* __restrict__ H2,
                                              const int* __restrict__ batch,
                                              float* __restrict__ pooled,
                                              float* __restrict__ cntg, int N) {
    const int c = threadIdx.x & 31;    // uint index within 128B row (2 channels)
    const int sub = threadIdx.x >> 5;  // 8 row-walkers per block
    const int base = blockIdx.x * 256;
    const int end = min(base + 256, N);
    float acc0 = 0.f, acc1 = 0.f, cacc = 0.f;
    int cur = -1;
    for (int i = base + sub; i < end; i += 8) {
        int g = batch[i];
        if (g != cur) {
            if (cur >= 0) {
                atomicAdd(&pooled[cur * 64 + 2 * c], acc0);
                atomicAdd(&pooled[cur * 64 + 2 * c + 1], acc1);
                if (c == 0) atomicAdd(&cntg[cur], cacc);
            }
            cur = g;
            acc0 = acc1 = cacc = 0.f;
        }
        unsigned int v = H2[(size_t)i * 32 + c];
        acc0 += bflo(v);
        acc1 += bfhi(v);
        cacc += 1.f;
    }
    if (cur >= 0) {
        atomicAdd(&pooled[cur * 64 + 2 * c], acc0);
        atomicAdd(&pooled[cur * 64 + 2 * c + 1], acc1);
        if (c == 0) atomicAdd(&cntg[cur], cacc);
    }
}

__global__ __launch_bounds__(64) void fc_k(const float* __restrict__ pooled,
                                           const float* __restrict__ cntg,
                                           const float* __restrict__ Wfc,
                                           const float* __restrict__ bfc,
                                           float* __restrict__ out) {
    __shared__ float p[64];
    const int g = blockIdx.x;
    const int t = threadIdx.x;
    const float cc = fmaxf(cntg[g], 1.0f);
    p[t] = pooled[g * 64 + t] / cc;
    __syncthreads();
    if (t < 10) {
        float a = bfc[t];
#pragma unroll
        for (int k = 0; k < 64; ++k) a = fmaf(p[k], Wfc[k * 10 + t], a);
        out[g * 10 + t] = a;
    }
}

extern "C" void kernel_launch(void* const* d_in, const int* in_sizes, int n_in,
                              void* d_out, int out_size, void* d_ws, size_t ws_size,
                              hipStream_t stream) {
    const float* x     = (const float*)d_in[0];
    const float* W1    = (const float*)d_in[1];
    const float* b1    = (const float*)d_in[2];
    const float* W2    = (const float*)d_in[3];
    const float* b2    = (const float*)d_in[4];
    const float* Wfc   = (const float*)d_in[5];
    const float* bfc   = (const float*)d_in[6];
    const int*   eidx  = (const int*)d_in[7];
    const int*   batch = (const int*)d_in[8];

    const int N = in_sizes[0] / 64;
    const int E = in_sizes[7] / 2;
    const int* erow = eidx;      // sources
    const int* ecol = eidx + E;  // destinations

    const int nbuck = (N + 511) >> 9;  // coarse buckets (<= 256)
    const int chunk = (E + NBLK_SORT - 1) / NBLK_SORT;

    char* ws = (char*)d_ws;
    size_t off = 0;
    auto alloc = [&](size_t bytes) -> void* {
        void* p = ws + off;
        off = (off + bytes + 511) & ~(size_t)511;
        return p;
    };
    uint2*        meta   = (uint2*)alloc((size_t)N * 8);
    float*        dinv   = (float*)alloc((size_t)N * 4);
    unsigned int* totals = (unsigned int*)alloc((size_t)nbuck * 4);
    unsigned int* bbase  = (unsigned int*)alloc((size_t)nbuck * 4);
    unsigned int* srcs   = (unsigned int*)alloc((size_t)E * 4);
    unsigned short* G16  = (unsigned short*)alloc((size_t)N * 64 * 2);
    unsigned short* H16  = (unsigned short*)alloc((size_t)N * 64 * 2);
    float*        pooled = (float*)alloc((size_t)(128 * 64 + 128) * 4);
    float*        cntg   = pooled + 128 * 64;

    // sort temporaries alias the H region (dead before H is first written)
    unsigned int* packed = (unsigned int*)H16;  // E*4 (needs E*4 <= N*128)
    unsigned int* bhist  = (unsigned int*)alloc((size_t)NBLK_SORT * nbuck * 4);
    unsigned int* bofs   = (unsigned int*)alloc((size_t)NBLK_SORT * nbuck * 4);

    const int ZN = 128 * 64 + 128;

    // --- CSR build: 2-level bucketed counting sort (+ pooled zeroing) ---
    hist_k<<<NBLK_SORT, 256, 0, stream>>>(ecol, bhist, pooled, ZN, E, chunk, nbuck);
    scanb_k<<<nbuck, 256, 0, stream>>>(bhist, bofs, totals, nbuck);
    scant_k<<<1, 256, 0, stream>>>(totals, bbase, nbuck);
    scatter_k<<<NBLK_SORT, 256, 0, stream>>>(erow, ecol, bbase, bofs, packed, E, chunk, nbuck);
    fine_k<<<nbuck, 512, 0, stream>>>(packed, bbase, totals, meta, dinv, srcs, N);

    const int aggB = (N + 31) / 32;  // 4 waves/block x 8 nodes/wave

    // --- layer 1 ---
    gemm_scale_k<false><<<1024, 256, 0, stream>>>(x, W1, dinv, G16, N);
    agg_k<<<aggB, 256, 0, stream>>>((const char*)G16, meta, srcs, dinv, b1, (uint4*)H16, N);

    // --- layer 2 ---
    gemm_scale_k<true><<<1024, 256, 0, stream>>>(H16, W2, dinv, G16, N);
    agg_k<<<aggB, 256, 0, stream>>>((const char*)G16, meta, srcs, dinv, b2, (uint4*)H16, N);

    // --- pooling + FC ---
    pool_k<<<(N + 255) / 256, 256, 0, stream>>>((const unsigned int*)H16, batch, pooled, cntg, N);
    fc_k<<<128, 64, 0, stream>>>(pooled, cntg, Wfc, bfc, (float*)d_out);
}

// Round 6
// 171.788 us; speedup vs baseline: 2.1581x; 1.0526x over previous
//
#include <hip/hip_runtime.h>
#include <cstdint>

// ---------------------------------------------------------------------------
// GCN forward: 2x (GEMM 64x64 -> symmetric-norm edge aggregation -> bias+ReLU)
// then global mean pool (sorted batch) and 64x10 FC.
//
// CSR build per call: 2-level bucketed counting sort (LDS atomics only):
//   hist_k -> scan_k (single block, wave scans) -> scatter_k -> fine_k
// GEMM via MFMA 16x16x32 bf16 (wave = 16 rows x 64 cols).
// Aggregation: wave = 8 nodes, 8 lanes/node, lane owns 8 channels, unroll 4.
// G and H stored bf16 (128 B/row).
// ---------------------------------------------------------------------------

#define NBLK_SORT 256

typedef __attribute__((ext_vector_type(8))) short bf16x8;
typedef __attribute__((ext_vector_type(4))) float f32x4;

static __device__ __forceinline__ unsigned int f2bf_r(float f) {
    unsigned int u = __float_as_uint(f);
    return u + 0x7FFFu + ((u >> 16) & 1u);  // rounded, needs >>16
}
static __device__ __forceinline__ float bflo(unsigned int v) {
    return __uint_as_float(v << 16);
}
static __device__ __forceinline__ float bfhi(unsigned int v) {
    return __uint_as_float(v & 0xFFFF0000u);
}

__global__ __launch_bounds__(256) void hist_k(const int* __restrict__ ecol,
                                              unsigned int* __restrict__ bhist,
                                              float* __restrict__ pooled_zero, int zn,
                                              int E, int chunk, int nbuck) {
    __shared__ unsigned int lh[256];
    lh[threadIdx.x] = 0u;
    __syncthreads();
    if (blockIdx.x == 0) {  // zero pooled+cntg (replaces in-graph memset)
        for (int i = threadIdx.x; i < zn; i += 256) pooled_zero[i] = 0.f;
    }
    const int s = blockIdx.x * chunk;
    const int e = min(s + chunk, E);
    for (int i = s + threadIdx.x; i < e; i += 256)
        atomicAdd(&lh[((unsigned int)ecol[i]) >> 9], 1u);
    __syncthreads();
    if ((int)threadIdx.x < nbuck)
        bhist[threadIdx.x * NBLK_SORT + blockIdx.x] = lh[threadIdx.x];
}

// single block: per-bucket exclusive scan over blocks (wave-parallel) +
// bucket-total scan -> bases. bhist/bofs layout [bucket][block].
__global__ __launch_bounds__(1024) void scan_k(const unsigned int* __restrict__ bhist,
                                               unsigned int* __restrict__ bofs,
                                               unsigned int* __restrict__ bbase,
                                               unsigned int* __restrict__ totals,
                                               int nbuck) {
    __shared__ unsigned int tls[256];
    const int wid = threadIdx.x >> 6;
    const int lane = threadIdx.x & 63;
    for (int b = wid; b < nbuck; b += 16) {
        uint4 v = ((const uint4*)(bhist + b * NBLK_SORT))[lane];
        unsigned int s = v.x + v.y + v.z + v.w;
        unsigned int inc = s;
#pragma unroll
        for (int d = 1; d < 64; d <<= 1) {
            unsigned int t = __shfl_up(inc, d, 64);
            if (lane >= d) inc += t;
        }
        unsigned int excl = inc - s;
        uint4 o;
        o.x = excl;
        o.y = excl + v.x;
        o.z = excl + v.x + v.y;
        o.w = excl + v.x + v.y + v.z;
        ((uint4*)(bofs + b * NBLK_SORT))[lane] = o;
        if (lane == 63) {
            tls[b] = inc;
            totals[b] = inc;
        }
    }
    __syncthreads();
    if (wid == 0) {
        unsigned int t0 = (lane * 4 + 0 < nbuck) ? tls[lane * 4 + 0] : 0u;
        unsigned int t1 = (lane * 4 + 1 < nbuck) ? tls[lane * 4 + 1] : 0u;
        unsigned int t2 = (lane * 4 + 2 < nbuck) ? tls[lane * 4 + 2] : 0u;
        unsigned int t3 = (lane * 4 + 3 < nbuck) ? tls[lane * 4 + 3] : 0u;
        unsigned int s = t0 + t1 + t2 + t3;
        unsigned int inc = s;
#pragma unroll
        for (int d = 1; d < 64; d <<= 1) {
            unsigned int t = __shfl_up(inc, d, 64);
            if (lane >= d) inc += t;
        }
        unsigned int excl = inc - s;
        if (lane * 4 + 0 < nbuck) bbase[lane * 4 + 0] = excl;
        if (lane * 4 + 1 < nbuck) bbase[lane * 4 + 1] = excl + t0;
        if (lane * 4 + 2 < nbuck) bbase[lane * 4 + 2] = excl + t0 + t1;
        if (lane * 4 + 3 < nbuck) bbase[lane * 4 + 3] = excl + t0 + t1 + t2;
    }
}

__global__ __launch_bounds__(256) void scatter_k(const int* __restrict__ erow,
                                                 const int* __restrict__ ecol,
                                                 const unsigned int* __restrict__ bbase,
                                                 const unsigned int* __restrict__ bofs,
                                                 unsigned int* __restrict__ packed,
                                                 int E, int chunk, int nbuck) {
    __shared__ unsigned int cur[256];
    if ((int)threadIdx.x < nbuck)
        cur[threadIdx.x] = bbase[threadIdx.x] + bofs[threadIdx.x * NBLK_SORT + blockIdx.x];
    __syncthreads();
    const int s = blockIdx.x * chunk;
    const int e = min(s + chunk, E);
    for (int i = s + threadIdx.x; i < e; i += 256) {
        unsigned int d = (unsigned int)ecol[i];
        unsigned int k = d >> 9;
        unsigned int p = atomicAdd(&cur[k], 1u);
        packed[p] = (((unsigned int)erow[i]) << 9) | (d & 511u);
    }
}

// one block per bucket: 512-bin fine sort; emits meta(offs,cnt)/dinv and srcs
__global__ __launch_bounds__(512) void fine_k(const unsigned int* __restrict__ packed,
                                              const unsigned int* __restrict__ bbase,
                                              const unsigned int* __restrict__ totals,
                                              uint2* __restrict__ meta,
                                              float* __restrict__ dinv,
                                              unsigned int* __restrict__ srcs, int N) {
    __shared__ unsigned int fh[512];
    __shared__ unsigned int sc[512];
    const int k = blockIdx.x;
    const int t = threadIdx.x;
    const unsigned int ebase = bbase[k];
    const unsigned int ecnt = totals[k];
    fh[t] = 0u;
    __syncthreads();
    for (unsigned int j = t; j < ecnt; j += 512)
        atomicAdd(&fh[packed[ebase + j] & 511u], 1u);
    __syncthreads();
    unsigned int v = fh[t];
    sc[t] = v;
    __syncthreads();
    for (int d = 1; d < 512; d <<= 1) {
        unsigned int u = (t >= d) ? sc[t - d] : 0u;
        __syncthreads();
        sc[t] += u;
        __syncthreads();
    }
    const unsigned int excl = sc[t] - v;
    const int node = (k << 9) + t;
    if (node < N) {
        meta[node] = make_uint2(ebase + excl, v);
        dinv[node] = rsqrtf((float)v + 1.0f);  // +1 self loop
    }
    __syncthreads();
    fh[t] = excl;  // reuse as cursor
    __syncthreads();
    for (unsigned int j = t; j < ecnt; j += 512) {
        unsigned int p = packed[ebase + j];
        unsigned int pos = atomicAdd(&fh[p & 511u], 1u);
        srcs[ebase + pos] = p >> 9;
    }
}

// MFMA GEMM: G16[r][c] = bf16((X[r,:] @ W[:,c]) * dinv[r])
// wave = 16 rows x 64 cols; 4 col-tiles x 2 k-steps of mfma_f32_16x16x32_bf16.
// A: lane holds X[rb*16 + (lane&15)][kg*8 + e + 32*s]; B: W[.][t*16 + (lane&15)].
template <bool BF16IN>
__global__ __launch_bounds__(256) void gemm_mfma_k(const void* __restrict__ Xv,
                                                   const float* __restrict__ W,
                                                   const float* __restrict__ dinv,
                                                   unsigned short* __restrict__ G16, int N) {
    const int lane = threadIdx.x & 63;
    const int col = lane & 15;
    const int kg = lane >> 4;  // 0..3
    bf16x8 wf[4][2];
#pragma unroll
    for (int t = 0; t < 4; ++t)
#pragma unroll
        for (int s = 0; s < 2; ++s)
#pragma unroll
            for (int e = 0; e < 8; ++e)
                wf[t][s][e] = (short)(f2bf_r(W[(s * 32 + kg * 8 + e) * 64 + t * 16 + col]) >> 16);

    const int wid = blockIdx.x * (blockDim.x >> 6) + (threadIdx.x >> 6);
    const int nw = gridDim.x * (blockDim.x >> 6);
    const int nrb = (N + 15) >> 4;
    for (int rb = wid; rb < nrb; rb += nw) {
        const int arow = rb * 16 + col;
        bf16x8 af[2];
        if (BF16IN) {
            const unsigned short* X = (const unsigned short*)Xv;
            const unsigned short* p = X + (size_t)arow * 64 + kg * 8;
            af[0] = *(const bf16x8*)p;
            af[1] = *(const bf16x8*)(p + 32);
        } else {
            const float* X = (const float*)Xv;
            const float* p = X + (size_t)arow * 64 + kg * 8;
#pragma unroll
            for (int s = 0; s < 2; ++s)
#pragma unroll
                for (int e = 0; e < 8; ++e)
                    af[s][e] = (short)(f2bf_r(p[s * 32 + e]) >> 16);
        }
        f32x4 zero = {0.0f, 0.0f, 0.0f, 0.0f};
        f32x4 acc0 = zero, acc1 = zero, acc2 = zero, acc3 = zero;
        acc0 = __builtin_amdgcn_mfma_f32_16x16x32_bf16(af[0], wf[0][0], acc0, 0, 0, 0);
        acc1 = __builtin_amdgcn_mfma_f32_16x16x32_bf16(af[0], wf[1][0], acc1, 0, 0, 0);
        acc2 = __builtin_amdgcn_mfma_f32_16x16x32_bf16(af[0], wf[2][0], acc2, 0, 0, 0);
        acc3 = __builtin_amdgcn_mfma_f32_16x16x32_bf16(af[0], wf[3][0], acc3, 0, 0, 0);
        acc0 = __builtin_amdgcn_mfma_f32_16x16x32_bf16(af[1], wf[0][1], acc0, 0, 0, 0);
        acc1 = __builtin_amdgcn_mfma_f32_16x16x32_bf16(af[1], wf[1][1], acc1, 0, 0, 0);
        acc2 = __builtin_amdgcn_mfma_f32_16x16x32_bf16(af[1], wf[2][1], acc2, 0, 0, 0);
        acc3 = __builtin_amdgcn_mfma_f32_16x16x32_bf16(af[1], wf[3][1], acc3, 0, 0, 0);
#pragma unroll
        for (int reg = 0; reg < 4; ++reg) {
            const int r = rb * 16 + kg * 4 + reg;
            if (r < N) {
                const float dv = dinv[r];
                unsigned short* gp = G16 + (size_t)r * 64 + col;
                gp[0]  = (unsigned short)(f2bf_r(acc0[reg] * dv) >> 16);
                gp[16] = (unsigned short)(f2bf_r(acc1[reg] * dv) >> 16);
                gp[32] = (unsigned short)(f2bf_r(acc2[reg] * dv) >> 16);
                gp[48] = (unsigned short)(f2bf_r(acc3[reg] * dv) >> 16);
            }
        }
    }
}

// H[node][:] = relu(dinv[node]*(G[node][:] + sum_src G[src][:]) + b)  (bf16 out)
// wave = 8 nodes; 8 lanes/node; lane owns 8 channels -> no cross-lane reduce.
__global__ __launch_bounds__(256) void agg_k(const char* __restrict__ Gb,
                                             const uint2* __restrict__ meta,
                                             const unsigned int* __restrict__ srcs,
                                             const float* __restrict__ dinv,
                                             const float* __restrict__ bias,
                                             uint4* __restrict__ H4, int N) {
    const int lane = threadIdx.x & 63;
    const int grp = lane >> 3;  // node slot within wave
    const int sub = lane & 7;   // uint4 index within the 128B row
    const int wid = blockIdx.x * (blockDim.x >> 6) + (threadIdx.x >> 6);
    const int node = wid * 8 + grp;
    if (node >= N) return;
    const uint2 oc = meta[node];
    const unsigned int o = oc.x;
    const unsigned int c = oc.y;
    const unsigned int suboff = (unsigned int)sub << 4;
    float a0 = 0.f, a1 = 0.f, a2 = 0.f, a3 = 0.f;
    float a4 = 0.f, a5 = 0.f, a6 = 0.f, a7 = 0.f;
#define ACCUM(v)                              \
    do {                                      \
        a0 += bflo((v).x); a1 += bfhi((v).x); \
        a2 += bflo((v).y); a3 += bfhi((v).y); \
        a4 += bflo((v).z); a5 += bfhi((v).z); \
        a6 += bflo((v).w); a7 += bfhi((v).w); \
    } while (0)
    unsigned int j = 0;
    for (; j + 4 <= c; j += 4) {
        unsigned int r0 = srcs[o + j];
        unsigned int r1 = srcs[o + j + 1];
        unsigned int r2 = srcs[o + j + 2];
        unsigned int r3 = srcs[o + j + 3];
        uint4 v0 = *(const uint4*)(Gb + ((r0 << 7) | suboff));
        uint4 v1 = *(const uint4*)(Gb + ((r1 << 7) | suboff));
        uint4 v2 = *(const uint4*)(Gb + ((r2 << 7) | suboff));
        uint4 v3 = *(const uint4*)(Gb + ((r3 << 7) | suboff));
        ACCUM(v0);
        ACCUM(v1);
        ACCUM(v2);
        ACCUM(v3);
    }
    for (; j < c; ++j) {
        unsigned int r = srcs[o + j];
        uint4 v = *(const uint4*)(Gb + ((r << 7) | suboff));
        ACCUM(v);
    }
    {  // self loop
        uint4 g = *(const uint4*)(Gb + (((unsigned int)node << 7) | suboff));
        ACCUM(g);
    }
#undef ACCUM
    const float dv = dinv[node];
    const float4 b0 = ((const float4*)bias)[sub * 2];
    const float4 b1 = ((const float4*)bias)[sub * 2 + 1];
    float o0 = fmaxf(fmaf(a0, dv, b0.x), 0.0f);
    float o1 = fmaxf(fmaf(a1, dv, b0.y), 0.0f);
    float o2 = fmaxf(fmaf(a2, dv, b0.z), 0.0f);
    float o3 = fmaxf(fmaf(a3, dv, b0.w), 0.0f);
    float o4 = fmaxf(fmaf(a4, dv, b1.x), 0.0f);
    float o5 = fmaxf(fmaf(a5, dv, b1.y), 0.0f);
    float o6 = fmaxf(fmaf(a6, dv, b1.z), 0.0f);
    float o7 = fmaxf(fmaf(a7, dv, b1.w), 0.0f);
    uint4 out;
    out.x = (f2bf_r(o0) >> 16) | (f2bf_r(o1) & 0xFFFF0000u);
    out.y = (f2bf_r(o2) >> 16) | (f2bf_r(o3) & 0xFFFF0000u);
    out.z = (f2bf_r(o4) >> 16) | (f2bf_r(o5) & 0xFFFF0000u);
    out.w = (f2bf_r(o6) >> 16) | (f2bf_r(o7) & 0xFFFF0000u);
    H4[(size_t)node * 8 + sub] = out;
}

// sorted-batch mean pool over bf16 H; lane owns 2 channels via uint loads
__global__ __launch_bounds__(256) void pool_k(const unsigned int* __restrict__ H2,
                                              const int* __restrict__ batch,
                                              float* __restrict__ pooled,
                                              float* __restrict__ cntg, int N) {
    const int c = threadIdx.x & 31;    // uint index within 128B row (2 channels)
    const int sub = threadIdx.x >> 5;  // 8 row-walkers per block
    const int base = blockIdx.x * 256;
    const int end = min(base + 256, N);
    float acc0 = 0.f, acc1 = 0.f, cacc = 0.f;
    int cur = -1;
    for (int i = base + sub; i < end; i += 8) {
        int g = batch[i];
        if (g != cur) {
            if (cur >= 0) {
                atomicAdd(&pooled[cur * 64 + 2 * c], acc0);
                atomicAdd(&pooled[cur * 64 + 2 * c + 1], acc1);
                if (c == 0) atomicAdd(&cntg[cur], cacc);
            }
            cur = g;
            acc0 = acc1 = cacc = 0.f;
        }
        unsigned int v = H2[(size_t)i * 32 + c];
        acc0 += bflo(v);
        acc1 += bfhi(v);
        cacc += 1.f;
    }
    if (cur >= 0) {
        atomicAdd(&pooled[cur * 64 + 2 * c], acc0);
        atomicAdd(&pooled[cur * 64 + 2 * c + 1], acc1);
        if (c == 0) atomicAdd(&cntg[cur], cacc);
    }
}

__global__ __launch_bounds__(64) void fc_k(const float* __restrict__ pooled,
                                           const float* __restrict__ cntg,
                                           const float* __restrict__ Wfc,
                                           const float* __restrict__ bfc,
                                           float* __restrict__ out) {
    __shared__ float p[64];
    const int g = blockIdx.x;
    const int t = threadIdx.x;
    const float cc = fmaxf(cntg[g], 1.0f);
    p[t] = pooled[g * 64 + t] / cc;
    __syncthreads();
    if (t < 10) {
        float a = bfc[t];
#pragma unroll
        for (int k = 0; k < 64; ++k) a = fmaf(p[k], Wfc[k * 10 + t], a);
        out[g * 10 + t] = a;
    }
}

extern "C" void kernel_launch(void* const* d_in, const int* in_sizes, int n_in,
                              void* d_out, int out_size, void* d_ws, size_t ws_size,
                              hipStream_t stream) {
    const float* x     = (const float*)d_in[0];
    const float* W1    = (const float*)d_in[1];
    const float* b1    = (const float*)d_in[2];
    const float* W2    = (const float*)d_in[3];
    const float* b2    = (const float*)d_in[4];
    const float* Wfc   = (const float*)d_in[5];
    const float* bfc   = (const float*)d_in[6];
    const int*   eidx  = (const int*)d_in[7];
    const int*   batch = (const int*)d_in[8];

    const int N = in_sizes[0] / 64;
    const int E = in_sizes[7] / 2;
    const int* erow = eidx;      // sources
    const int* ecol = eidx + E;  // destinations

    const int nbuck = (N + 511) >> 9;  // coarse buckets (<= 256)
    const int chunk = (E + NBLK_SORT - 1) / NBLK_SORT;

    char* ws = (char*)d_ws;
    size_t off = 0;
    auto alloc = [&](size_t bytes) -> void* {
        void* p = ws + off;
        off = (off + bytes + 511) & ~(size_t)511;
        return p;
    };
    uint2*        meta   = (uint2*)alloc((size_t)N * 8);
    float*        dinv   = (float*)alloc((size_t)N * 4);
    unsigned int* totals = (unsigned int*)alloc((size_t)nbuck * 4);
    unsigned int* bbase  = (unsigned int*)alloc((size_t)nbuck * 4);
    unsigned int* srcs   = (unsigned int*)alloc((size_t)E * 4);
    unsigned short* G16  = (unsigned short*)alloc((size_t)N * 64 * 2);
    unsigned short* H16  = (unsigned short*)alloc((size_t)N * 64 * 2);
    float*        pooled = (float*)alloc((size_t)(128 * 64 + 128) * 4);
    float*        cntg   = pooled + 128 * 64;

    // sort temporaries alias the H region (dead before H is first written)
    unsigned int* packed = (unsigned int*)H16;  // E*4 (needs E*4 <= N*128)
    unsigned int* bhist  = (unsigned int*)alloc((size_t)NBLK_SORT * 256 * 4);
    unsigned int* bofs   = (unsigned int*)alloc((size_t)NBLK_SORT * 256 * 4);

    const int ZN = 128 * 64 + 128;

    // --- CSR build: 2-level bucketed counting sort (+ pooled zeroing) ---
    hist_k<<<NBLK_SORT, 256, 0, stream>>>(ecol, bhist, pooled, ZN, E, chunk, nbuck);
    scan_k<<<1, 1024, 0, stream>>>(bhist, bofs, bbase, totals, nbuck);
    scatter_k<<<NBLK_SORT, 256, 0, stream>>>(erow, ecol, bbase, bofs, packed, E, chunk, nbuck);
    fine_k<<<nbuck, 512, 0, stream>>>(packed, bbase, totals, meta, dinv, srcs, N);

    const int aggB = (N + 31) / 32;  // 4 waves/block x 8 nodes/wave

    // --- layer 1 ---
    gemm_mfma_k<false><<<128, 256, 0, stream>>>(x, W1, dinv, G16, N);
    agg_k<<<aggB, 256, 0, stream>>>((const char*)G16, meta, srcs, dinv, b1, (uint4*)H16, N);

    // --- layer 2 ---
    gemm_mfma_k<true><<<128, 256, 0, stream>>>(H16, W2, dinv, G16, N);
    agg_k<<<aggB, 256, 0, stream>>>((const char*)G16, meta, srcs, dinv, b2, (uint4*)H16, N);

    // --- pooling + FC ---
    pool_k<<<(N + 255) / 256, 256, 0, stream>>>((const unsigned int*)H16, batch, pooled, cntg, N);
    fc_k<<<128, 64, 0, stream>>>(pooled, cntg, Wfc, bfc, (float*)d_out);
}

// Round 7
// 170.451 us; speedup vs baseline: 2.1750x; 1.0078x over previous
//
#include <hip/hip_runtime.h>
#include <cstdint>

// ---------------------------------------------------------------------------
// GCN forward: 2x (GEMM 64x64 -> symmetric-norm edge aggregation -> bias+ReLU)
// then global mean pool (sorted batch) and 64x10 FC.
//
// CSR build per call: 2-level bucketed counting sort (LDS atomics only):
//   hist_k -> scan_k (single block) -> scatter_k -> fine_k
// GEMM via MFMA 16x16x32 bf16 (wave = 16 rows x 64 cols).
// Aggregation: wave = 8 nodes, 8 lanes/node, lane owns 8 channels; block's
// contiguous srcs window staged in LDS; srcs pre-shifted to byte offsets.
// Pool+FC fused: one block per graph, binary search on sorted batch.
// G and H stored bf16 (128 B/row).
// ---------------------------------------------------------------------------

#define NBLK_SORT 256
#define SCAP 768  // LDS srcs window entries per agg block (32 nodes, ~384 avg)

typedef __attribute__((ext_vector_type(8))) short bf16x8;
typedef __attribute__((ext_vector_type(4))) float f32x4;

static __device__ __forceinline__ unsigned int f2bf_r(float f) {
    unsigned int u = __float_as_uint(f);
    return u + 0x7FFFu + ((u >> 16) & 1u);  // rounded, needs >>16
}
static __device__ __forceinline__ float bflo(unsigned int v) {
    return __uint_as_float(v << 16);
}
static __device__ __forceinline__ float bfhi(unsigned int v) {
    return __uint_as_float(v & 0xFFFF0000u);
}

__global__ __launch_bounds__(256) void hist_k(const int* __restrict__ ecol,
                                              unsigned int* __restrict__ bhist,
                                              int E, int chunk, int nbuck) {
    __shared__ unsigned int lh[256];
    lh[threadIdx.x] = 0u;
    __syncthreads();
    const int s = blockIdx.x * chunk;
    const int e = min(s + chunk, E);
    const int n4 = (e - s) >> 2;
    const uint4* ec4 = (const uint4*)(ecol + s);
    for (int i = threadIdx.x; i < n4; i += 256) {
        uint4 v = ec4[i];
        atomicAdd(&lh[v.x >> 9], 1u);
        atomicAdd(&lh[v.y >> 9], 1u);
        atomicAdd(&lh[v.z >> 9], 1u);
        atomicAdd(&lh[v.w >> 9], 1u);
    }
    // scalar tail (span not multiple of 4)
    for (int i = s + (n4 << 2) + threadIdx.x; i < e; i += 256)
        atomicAdd(&lh[((unsigned int)ecol[i]) >> 9], 1u);
    __syncthreads();
    if ((int)threadIdx.x < nbuck)
        bhist[threadIdx.x * NBLK_SORT + blockIdx.x] = lh[threadIdx.x];
}

// single block: per-bucket exclusive scan over blocks (wave-parallel) +
// bucket-total scan -> bases. bhist/bofs layout [bucket][block].
__global__ __launch_bounds__(1024) void scan_k(const unsigned int* __restrict__ bhist,
                                               unsigned int* __restrict__ bofs,
                                               unsigned int* __restrict__ bbase,
                                               unsigned int* __restrict__ totals,
                                               int nbuck) {
    __shared__ unsigned int tls[256];
    const int wid = threadIdx.x >> 6;
    const int lane = threadIdx.x & 63;
    for (int b = wid; b < nbuck; b += 16) {
        uint4 v = ((const uint4*)(bhist + b * NBLK_SORT))[lane];
        unsigned int s = v.x + v.y + v.z + v.w;
        unsigned int inc = s;
#pragma unroll
        for (int d = 1; d < 64; d <<= 1) {
            unsigned int t = __shfl_up(inc, d, 64);
            if (lane >= d) inc += t;
        }
        unsigned int excl = inc - s;
        uint4 o;
        o.x = excl;
        o.y = excl + v.x;
        o.z = excl + v.x + v.y;
        o.w = excl + v.x + v.y + v.z;
        ((uint4*)(bofs + b * NBLK_SORT))[lane] = o;
        if (lane == 63) {
            tls[b] = inc;
            totals[b] = inc;
        }
    }
    __syncthreads();
    if (wid == 0) {
        unsigned int t0 = (lane * 4 + 0 < nbuck) ? tls[lane * 4 + 0] : 0u;
        unsigned int t1 = (lane * 4 + 1 < nbuck) ? tls[lane * 4 + 1] : 0u;
        unsigned int t2 = (lane * 4 + 2 < nbuck) ? tls[lane * 4 + 2] : 0u;
        unsigned int t3 = (lane * 4 + 3 < nbuck) ? tls[lane * 4 + 3] : 0u;
        unsigned int s = t0 + t1 + t2 + t3;
        unsigned int inc = s;
#pragma unroll
        for (int d = 1; d < 64; d <<= 1) {
            unsigned int t = __shfl_up(inc, d, 64);
            if (lane >= d) inc += t;
        }
        unsigned int excl = inc - s;
        if (lane * 4 + 0 < nbuck) bbase[lane * 4 + 0] = excl;
        if (lane * 4 + 1 < nbuck) bbase[lane * 4 + 1] = excl + t0;
        if (lane * 4 + 2 < nbuck) bbase[lane * 4 + 2] = excl + t0 + t1;
        if (lane * 4 + 3 < nbuck) bbase[lane * 4 + 3] = excl + t0 + t1 + t2;
    }
}

__global__ __launch_bounds__(256) void scatter_k(const int* __restrict__ erow,
                                                 const int* __restrict__ ecol,
                                                 const unsigned int* __restrict__ bbase,
                                                 const unsigned int* __restrict__ bofs,
                                                 unsigned int* __restrict__ packed,
                                                 int E, int chunk, int nbuck) {
    __shared__ unsigned int cur[256];
    if ((int)threadIdx.x < nbuck)
        cur[threadIdx.x] = bbase[threadIdx.x] + bofs[threadIdx.x * NBLK_SORT + blockIdx.x];
    __syncthreads();
    const int s = blockIdx.x * chunk;
    const int e = min(s + chunk, E);
    const int n4 = (e - s) >> 2;
    const uint4* ec4 = (const uint4*)(ecol + s);
    const uint4* er4 = (const uint4*)(erow + s);
    for (int i = threadIdx.x; i < n4; i += 256) {
        uint4 d = ec4[i];
        uint4 r = er4[i];
        unsigned int p;
        p = atomicAdd(&cur[d.x >> 9], 1u); packed[p] = (r.x << 9) | (d.x & 511u);
        p = atomicAdd(&cur[d.y >> 9], 1u); packed[p] = (r.y << 9) | (d.y & 511u);
        p = atomicAdd(&cur[d.z >> 9], 1u); packed[p] = (r.z << 9) | (d.z & 511u);
        p = atomicAdd(&cur[d.w >> 9], 1u); packed[p] = (r.w << 9) | (d.w & 511u);
    }
    for (int i = s + (n4 << 2) + threadIdx.x; i < e; i += 256) {
        unsigned int d = (unsigned int)ecol[i];
        unsigned int p = atomicAdd(&cur[d >> 9], 1u);
        packed[p] = (((unsigned int)erow[i]) << 9) | (d & 511u);
    }
}

// one block per bucket: 512-bin fine sort; emits meta(offs,cnt)/dinv and srcs
// srcs are stored PRE-SHIFTED to byte offsets (src * 128).
__global__ __launch_bounds__(512) void fine_k(const unsigned int* __restrict__ packed,
                                              const unsigned int* __restrict__ bbase,
                                              const unsigned int* __restrict__ totals,
                                              uint2* __restrict__ meta,
                                              float* __restrict__ dinv,
                                              unsigned int* __restrict__ srcs, int N) {
    __shared__ unsigned int fh[512];
    __shared__ unsigned int sc[512];
    const int k = blockIdx.x;
    const int t = threadIdx.x;
    const unsigned int ebase = bbase[k];
    const unsigned int ecnt = totals[k];
    fh[t] = 0u;
    __syncthreads();
    for (unsigned int j = t; j < ecnt; j += 512)
        atomicAdd(&fh[packed[ebase + j] & 511u], 1u);
    __syncthreads();
    unsigned int v = fh[t];
    sc[t] = v;
    __syncthreads();
    for (int d = 1; d < 512; d <<= 1) {
        unsigned int u = (t >= d) ? sc[t - d] : 0u;
        __syncthreads();
        sc[t] += u;
        __syncthreads();
    }
    const unsigned int excl = sc[t] - v;
    const int node = (k << 9) + t;
    if (node < N) {
        meta[node] = make_uint2(ebase + excl, v);
        dinv[node] = rsqrtf((float)v + 1.0f);  // +1 self loop
    }
    __syncthreads();
    fh[t] = excl;  // reuse as cursor
    __syncthreads();
    for (unsigned int j = t; j < ecnt; j += 512) {
        unsigned int p = packed[ebase + j];
        unsigned int pos = atomicAdd(&fh[p & 511u], 1u);
        srcs[ebase + pos] = (p >> 9) << 7;  // byte offset of source row
    }
}

// MFMA GEMM: G16[r][c] = bf16((X[r,:] @ W[:,c]) * dinv[r])
// wave = 16 rows x 64 cols; 4 col-tiles x 2 k-steps of mfma_f32_16x16x32_bf16.
template <bool BF16IN>
__global__ __launch_bounds__(256) void gemm_mfma_k(const void* __restrict__ Xv,
                                                   const float* __restrict__ W,
                                                   const float* __restrict__ dinv,
                                                   unsigned short* __restrict__ G16, int N) {
    const int lane = threadIdx.x & 63;
    const int col = lane & 15;
    const int kg = lane >> 4;  // 0..3
    bf16x8 wf[4][2];
#pragma unroll
    for (int t = 0; t < 4; ++t)
#pragma unroll
        for (int s = 0; s < 2; ++s)
#pragma unroll
            for (int e = 0; e < 8; ++e)
                wf[t][s][e] = (short)(f2bf_r(W[(s * 32 + kg * 8 + e) * 64 + t * 16 + col]) >> 16);

    const int wid = blockIdx.x * (blockDim.x >> 6) + (threadIdx.x >> 6);
    const int nw = gridDim.x * (blockDim.x >> 6);
    const int nrb = (N + 15) >> 4;
    for (int rb = wid; rb < nrb; rb += nw) {
        const int arow = rb * 16 + col;
        bf16x8 af[2];
        if (BF16IN) {
            const unsigned short* X = (const unsigned short*)Xv;
            const unsigned short* p = X + (size_t)arow * 64 + kg * 8;
            af[0] = *(const bf16x8*)p;
            af[1] = *(const bf16x8*)(p + 32);
        } else {
            const float* X = (const float*)Xv;
            const float4* p = (const float4*)(X + (size_t)arow * 64 + kg * 8);
            float4 q0 = p[0], q1 = p[1], q2 = p[8], q3 = p[9];
            af[0][0] = (short)(f2bf_r(q0.x) >> 16); af[0][1] = (short)(f2bf_r(q0.y) >> 16);
            af[0][2] = (short)(f2bf_r(q0.z) >> 16); af[0][3] = (short)(f2bf_r(q0.w) >> 16);
            af[0][4] = (short)(f2bf_r(q1.x) >> 16); af[0][5] = (short)(f2bf_r(q1.y) >> 16);
            af[0][6] = (short)(f2bf_r(q1.z) >> 16); af[0][7] = (short)(f2bf_r(q1.w) >> 16);
            af[1][0] = (short)(f2bf_r(q2.x) >> 16); af[1][1] = (short)(f2bf_r(q2.y) >> 16);
            af[1][2] = (short)(f2bf_r(q2.z) >> 16); af[1][3] = (short)(f2bf_r(q2.w) >> 16);
            af[1][4] = (short)(f2bf_r(q3.x) >> 16); af[1][5] = (short)(f2bf_r(q3.y) >> 16);
            af[1][6] = (short)(f2bf_r(q3.z) >> 16); af[1][7] = (short)(f2bf_r(q3.w) >> 16);
        }
        f32x4 zero = {0.0f, 0.0f, 0.0f, 0.0f};
        f32x4 acc0 = zero, acc1 = zero, acc2 = zero, acc3 = zero;
        acc0 = __builtin_amdgcn_mfma_f32_16x16x32_bf16(af[0], wf[0][0], acc0, 0, 0, 0);
        acc1 = __builtin_amdgcn_mfma_f32_16x16x32_bf16(af[0], wf[1][0], acc1, 0, 0, 0);
        acc2 = __builtin_amdgcn_mfma_f32_16x16x32_bf16(af[0], wf[2][0], acc2, 0, 0, 0);
        acc3 = __builtin_amdgcn_mfma_f32_16x16x32_bf16(af[0], wf[3][0], acc3, 0, 0, 0);
        acc0 = __builtin_amdgcn_mfma_f32_16x16x32_bf16(af[1], wf[0][1], acc0, 0, 0, 0);
        acc1 = __builtin_amdgcn_mfma_f32_16x16x32_bf16(af[1], wf[1][1], acc1, 0, 0, 0);
        acc2 = __builtin_amdgcn_mfma_f32_16x16x32_bf16(af[1], wf[2][1], acc2, 0, 0, 0);
        acc3 = __builtin_amdgcn_mfma_f32_16x16x32_bf16(af[1], wf[3][1], acc3, 0, 0, 0);
#pragma unroll
        for (int reg = 0; reg < 4; ++reg) {
            const int r = rb * 16 + kg * 4 + reg;
            if (r < N) {
                const float dv = dinv[r];
                unsigned short* gp = G16 + (size_t)r * 64 + col;
                gp[0]  = (unsigned short)(f2bf_r(acc0[reg] * dv) >> 16);
                gp[16] = (unsigned short)(f2bf_r(acc1[reg] * dv) >> 16);
                gp[32] = (unsigned short)(f2bf_r(acc2[reg] * dv) >> 16);
                gp[48] = (unsigned short)(f2bf_r(acc3[reg] * dv) >> 16);
            }
        }
    }
}

// H[node][:] = relu(dinv[node]*(G[node][:] + sum_src G[src][:]) + b)  (bf16 out)
// wave = 8 nodes; 8 lanes/node; lane owns 8 channels. Block's contiguous srcs
// window staged in LDS (srcs hold byte offsets already).
__global__ __launch_bounds__(256) void agg_k(const char* __restrict__ Gb,
                                             const uint2* __restrict__ meta,
                                             const unsigned int* __restrict__ srcs,
                                             const float* __restrict__ dinv,
                                             const float* __restrict__ bias,
                                             uint4* __restrict__ H4, int N) {
    __shared__ unsigned int slds[SCAP];
    const int nodeBase = blockIdx.x * 32;
    const int nLast = min(nodeBase + 31, N - 1);
    const unsigned int base = meta[nodeBase].x;
    const uint2 lastm = meta[nLast];
    const unsigned int blen = lastm.x + lastm.y - base;
    for (unsigned int i = threadIdx.x; i < blen && i < SCAP; i += 256)
        slds[i] = srcs[base + i];
    __syncthreads();

    const int lane = threadIdx.x & 63;
    const int grp = lane >> 3;  // node slot within wave
    const int sub = lane & 7;   // uint4 index within the 128B row
    const int node = nodeBase + (threadIdx.x >> 6) * 8 + grp;
    if (node >= N) return;
    const uint2 oc = meta[node];
    const unsigned int orel = oc.x - base;
    const unsigned int c = oc.y;
    const unsigned int suboff = (unsigned int)sub << 4;
#define LDSRC(i) ((i) < SCAP ? slds[i] : srcs[base + (i)])
    float a0 = 0.f, a1 = 0.f, a2 = 0.f, a3 = 0.f;
    float a4 = 0.f, a5 = 0.f, a6 = 0.f, a7 = 0.f;
#define ACCUM(v)                              \
    do {                                      \
        a0 += bflo((v).x); a1 += bfhi((v).x); \
        a2 += bflo((v).y); a3 += bfhi((v).y); \
        a4 += bflo((v).z); a5 += bfhi((v).z); \
        a6 += bflo((v).w); a7 += bfhi((v).w); \
    } while (0)
    unsigned int j = 0;
    for (; j + 4 <= c; j += 4) {
        unsigned int s0 = LDSRC(orel + j);
        unsigned int s1 = LDSRC(orel + j + 1);
        unsigned int s2 = LDSRC(orel + j + 2);
        unsigned int s3 = LDSRC(orel + j + 3);
        uint4 v0 = *(const uint4*)(Gb + (s0 | suboff));
        uint4 v1 = *(const uint4*)(Gb + (s1 | suboff));
        uint4 v2 = *(const uint4*)(Gb + (s2 | suboff));
        uint4 v3 = *(const uint4*)(Gb + (s3 | suboff));
        ACCUM(v0);
        ACCUM(v1);
        ACCUM(v2);
        ACCUM(v3);
    }
    for (; j < c; ++j) {
        unsigned int s = LDSRC(orel + j);
        uint4 v = *(const uint4*)(Gb + (s | suboff));
        ACCUM(v);
    }
    {  // self loop
        uint4 g = *(const uint4*)(Gb + (((unsigned int)node << 7) | suboff));
        ACCUM(g);
    }
#undef ACCUM
#undef LDSRC
    const float dv = dinv[node];
    const float4 b0 = ((const float4*)bias)[sub * 2];
    const float4 b1 = ((const float4*)bias)[sub * 2 + 1];
    float o0 = fmaxf(fmaf(a0, dv, b0.x), 0.0f);
    float o1 = fmaxf(fmaf(a1, dv, b0.y), 0.0f);
    float o2 = fmaxf(fmaf(a2, dv, b0.z), 0.0f);
    float o3 = fmaxf(fmaf(a3, dv, b0.w), 0.0f);
    float o4 = fmaxf(fmaf(a4, dv, b1.x), 0.0f);
    float o5 = fmaxf(fmaf(a5, dv, b1.y), 0.0f);
    float o6 = fmaxf(fmaf(a6, dv, b1.z), 0.0f);
    float o7 = fmaxf(fmaf(a7, dv, b1.w), 0.0f);
    uint4 out;
    out.x = (f2bf_r(o0) >> 16) | (f2bf_r(o1) & 0xFFFF0000u);
    out.y = (f2bf_r(o2) >> 16) | (f2bf_r(o3) & 0xFFFF0000u);
    out.z = (f2bf_r(o4) >> 16) | (f2bf_r(o5) & 0xFFFF0000u);
    out.w = (f2bf_r(o6) >> 16) | (f2bf_r(o7) & 0xFFFF0000u);
    H4[(size_t)node * 8 + sub] = out;
}

// fused mean-pool + FC: one block per graph; batch is sorted so graph g's
// rows are the contiguous range [lb(g), lb(g+1)).
__global__ __launch_bounds__(256) void graph_k(const unsigned int* __restrict__ H2,
                                               const int* __restrict__ batch,
                                               const float* __restrict__ Wfc,
                                               const float* __restrict__ bfc,
                                               float* __restrict__ out, int N) {
    __shared__ float sh[8 * 64];
    __shared__ float p[64];
    const int g = blockIdx.x;
    const int t = threadIdx.x;
    // lower bounds
    int lo = 0, hi = N;
    while (lo < hi) {
        int mid = (lo + hi) >> 1;
        if (batch[mid] < g) lo = mid + 1; else hi = mid;
    }
    const int start = lo;
    hi = N;
    while (lo < hi) {
        int mid = (lo + hi) >> 1;
        if (batch[mid] < g + 1) lo = mid + 1; else hi = mid;
    }
    const int end = lo;

    const int w = t >> 5;   // 8 row-walkers
    const int c = t & 31;   // uint index (2 channels)
    float acc0 = 0.f, acc1 = 0.f;
    for (int i = start + w; i < end; i += 8) {
        unsigned int v = H2[(size_t)i * 32 + c];
        acc0 += bflo(v);
        acc1 += bfhi(v);
    }
    sh[w * 64 + 2 * c] = acc0;
    sh[w * 64 + 2 * c + 1] = acc1;
    __syncthreads();
    if (t < 64) {
        float s = 0.f;
#pragma unroll
        for (int i = 0; i < 8; ++i) s += sh[i * 64 + t];
        p[t] = s / (float)max(end - start, 1);
    }
    __syncthreads();
    if (t < 10) {
        float a = bfc[t];
#pragma unroll
        for (int k = 0; k < 64; ++k) a = fmaf(p[k], Wfc[k * 10 + t], a);
        out[g * 10 + t] = a;
    }
}

extern "C" void kernel_launch(void* const* d_in, const int* in_sizes, int n_in,
                              void* d_out, int out_size, void* d_ws, size_t ws_size,
                              hipStream_t stream) {
    const float* x     = (const float*)d_in[0];
    const float* W1    = (const float*)d_in[1];
    const float* b1    = (const float*)d_in[2];
    const float* W2    = (const float*)d_in[3];
    const float* b2    = (const float*)d_in[4];
    const float* Wfc   = (const float*)d_in[5];
    const float* bfc   = (const float*)d_in[6];
    const int*   eidx  = (const int*)d_in[7];
    const int*   batch = (const int*)d_in[8];

    const int N = in_sizes[0] / 64;
    const int E = in_sizes[7] / 2;
    const int G = out_size / 10;
    const int* erow = eidx;      // sources
    const int* ecol = eidx + E;  // destinations

    const int nbuck = (N + 511) >> 9;  // coarse buckets (<= 256)
    const int chunk = (((E + NBLK_SORT - 1) / NBLK_SORT) + 3) & ~3;

    char* ws = (char*)d_ws;
    size_t off = 0;
    auto alloc = [&](size_t bytes) -> void* {
        void* p = ws + off;
        off = (off + bytes + 511) & ~(size_t)511;
        return p;
    };
    uint2*        meta   = (uint2*)alloc((size_t)N * 8);
    float*        dinv   = (float*)alloc((size_t)N * 4);
    unsigned int* totals = (unsigned int*)alloc((size_t)nbuck * 4);
    unsigned int* bbase  = (unsigned int*)alloc((size_t)nbuck * 4);
    unsigned int* srcs   = (unsigned int*)alloc((size_t)E * 4);
    unsigned short* G16  = (unsigned short*)alloc((size_t)N * 64 * 2);
    unsigned short* H16  = (unsigned short*)alloc((size_t)N * 64 * 2);

    // sort temporaries alias the H region (dead before H is first written)
    unsigned int* packed = (unsigned int*)H16;  // E*4 (needs E*4 <= N*128)
    unsigned int* bhist  = (unsigned int*)alloc((size_t)NBLK_SORT * 256 * 4);
    unsigned int* bofs   = (unsigned int*)alloc((size_t)NBLK_SORT * 256 * 4);

    // --- CSR build: 2-level bucketed counting sort ---
    hist_k<<<NBLK_SORT, 256, 0, stream>>>(ecol, bhist, E, chunk, nbuck);
    scan_k<<<1, 1024, 0, stream>>>(bhist, bofs, bbase, totals, nbuck);
    scatter_k<<<NBLK_SORT, 256, 0, stream>>>(erow, ecol, bbase, bofs, packed, E, chunk, nbuck);
    fine_k<<<nbuck, 512, 0, stream>>>(packed, bbase, totals, meta, dinv, srcs, N);

    const int aggB = (N + 31) / 32;  // 4 waves/block x 8 nodes/wave

    // --- layer 1 ---
    gemm_mfma_k<false><<<128, 256, 0, stream>>>(x, W1, dinv, G16, N);
    agg_k<<<aggB, 256, 0, stream>>>((const char*)G16, meta, srcs, dinv, b1, (uint4*)H16, N);

    // --- layer 2 ---
    gemm_mfma_k<true><<<128, 256, 0, stream>>>(H16, W2, dinv, G16, N);
    agg_k<<<aggB, 256, 0, stream>>>((const char*)G16, meta, srcs, dinv, b2, (uint4*)H16, N);

    // --- fused mean-pool + FC ---
    graph_k<<<G, 256, 0, stream>>>((const unsigned int*)H16, batch, Wfc, bfc,
                                   (float*)d_out, N);
}

// Round 8
// 136.929 us; speedup vs baseline: 2.7075x; 1.2448x over previous
//
#include <hip/hip_runtime.h>
#include <cstdint>

// ---------------------------------------------------------------------------
// GCN forward: 2x (GEMM 64x64 -> symmetric-norm edge aggregation -> bias+ReLU)
// then global mean pool (sorted batch) and 64x10 FC.
//
// 7 dispatches:
//   hist_k     : per-block LDS histogram of coarse bucket (dst>>9)
//   scatter2_k : self-computes bases+prefix from bhist (scan fused), scatters
//   fine_k     : per-bucket 512-bin sort -> srcs CSR (byte offsets) + meta/dinv
//   gemm1      : MFMA 16x16x32 bf16, x(f32) @ W1 -> G16 (*dinv, bf16)
//   agg_gemm_k : agg layer1 (gather) -> H tile in LDS (swizzled) -> MFMA @ W2
//                -> G2 (*dinv, bf16)   [H never hits global memory]
//   agg_k      : agg layer2 (gather) -> H16 (bf16)
//   graph_k    : fused mean-pool (binary search on sorted batch) + FC
// ---------------------------------------------------------------------------

#define NBLK_SORT 256
#define SCAP 768  // LDS srcs window entries per agg block (32 nodes, ~384 avg)

typedef __attribute__((ext_vector_type(8))) short bf16x8;
typedef __attribute__((ext_vector_type(4))) float f32x4;

static __device__ __forceinline__ unsigned int f2bf_r(float f) {
    unsigned int u = __float_as_uint(f);
    return u + 0x7FFFu + ((u >> 16) & 1u);  // rounded, needs >>16
}
static __device__ __forceinline__ float bflo(unsigned int v) {
    return __uint_as_float(v << 16);
}
static __device__ __forceinline__ float bfhi(unsigned int v) {
    return __uint_as_float(v & 0xFFFF0000u);
}

__global__ __launch_bounds__(256) void hist_k(const int* __restrict__ ecol,
                                              unsigned int* __restrict__ bhist,
                                              int E, int chunk, int nbuck) {
    __shared__ unsigned int lh[256];
    lh[threadIdx.x] = 0u;
    __syncthreads();
    const int s = blockIdx.x * chunk;
    const int e = min(s + chunk, E);
    const int n4 = (e - s) >> 2;
    const uint4* ec4 = (const uint4*)(ecol + s);
    for (int i = threadIdx.x; i < n4; i += 256) {
        uint4 v = ec4[i];
        atomicAdd(&lh[v.x >> 9], 1u);
        atomicAdd(&lh[v.y >> 9], 1u);
        atomicAdd(&lh[v.z >> 9], 1u);
        atomicAdd(&lh[v.w >> 9], 1u);
    }
    for (int i = s + (n4 << 2) + threadIdx.x; i < e; i += 256)
        atomicAdd(&lh[((unsigned int)ecol[i]) >> 9], 1u);
    __syncthreads();
    if ((int)threadIdx.x < nbuck)
        bhist[threadIdx.x * NBLK_SORT + blockIdx.x] = lh[threadIdx.x];
}

// scatter with fused scan: each block recomputes bucket totals + its own
// prefix from bhist ([bucket][block] layout); block 0 publishes bbase/totals.
__global__ __launch_bounds__(256) void scatter2_k(const int* __restrict__ erow,
                                                  const int* __restrict__ ecol,
                                                  const unsigned int* __restrict__ bhist,
                                                  unsigned int* __restrict__ bbase_out,
                                                  unsigned int* __restrict__ totals_out,
                                                  unsigned int* __restrict__ packed,
                                                  int E, int chunk, int nbuck) {
    __shared__ unsigned int cur[256];
    __shared__ unsigned int sc[256];
    const int t = threadIdx.x;
    const int blk = blockIdx.x;
    unsigned int total = 0u, mine = 0u;
    if (t < nbuck) {
        const uint4* h4 = (const uint4*)(bhist + t * NBLK_SORT);
#pragma unroll 8
        for (int i = 0; i < NBLK_SORT / 4; ++i) {
            uint4 v = h4[i];
            const int b0 = i * 4;
            total += v.x + v.y + v.z + v.w;
            mine += (b0 + 0 < blk ? v.x : 0u) + (b0 + 1 < blk ? v.y : 0u) +
                    (b0 + 2 < blk ? v.z : 0u) + (b0 + 3 < blk ? v.w : 0u);
        }
    }
    sc[t] = (t < nbuck) ? total : 0u;
    __syncthreads();
    for (int d = 1; d < 256; d <<= 1) {
        unsigned int u = (t >= d) ? sc[t - d] : 0u;
        __syncthreads();
        sc[t] += u;
        __syncthreads();
    }
    const unsigned int base = sc[t] - ((t < nbuck) ? total : 0u);  // exclusive
    if (t < nbuck) {
        cur[t] = base + mine;
        if (blk == 0) {
            bbase_out[t] = base;
            totals_out[t] = total;
        }
    }
    __syncthreads();
    const int s = blk * chunk;
    const int e = min(s + chunk, E);
    const int n4 = (e - s) >> 2;
    const uint4* ec4 = (const uint4*)(ecol + s);
    const uint4* er4 = (const uint4*)(erow + s);
    for (int i = t; i < n4; i += 256) {
        uint4 d = ec4[i];
        uint4 r = er4[i];
        unsigned int p;
        p = atomicAdd(&cur[d.x >> 9], 1u); packed[p] = (r.x << 9) | (d.x & 511u);
        p = atomicAdd(&cur[d.y >> 9], 1u); packed[p] = (r.y << 9) | (d.y & 511u);
        p = atomicAdd(&cur[d.z >> 9], 1u); packed[p] = (r.z << 9) | (d.z & 511u);
        p = atomicAdd(&cur[d.w >> 9], 1u); packed[p] = (r.w << 9) | (d.w & 511u);
    }
    for (int i = s + (n4 << 2) + t; i < e; i += 256) {
        unsigned int d = (unsigned int)ecol[i];
        unsigned int p = atomicAdd(&cur[d >> 9], 1u);
        packed[p] = (((unsigned int)erow[i]) << 9) | (d & 511u);
    }
}

// one block per bucket: 512-bin fine sort; emits meta(offs,cnt)/dinv and srcs
// srcs are stored PRE-SHIFTED to byte offsets (src * 128).
__global__ __launch_bounds__(512) void fine_k(const unsigned int* __restrict__ packed,
                                              const unsigned int* __restrict__ bbase,
                                              const unsigned int* __restrict__ totals,
                                              uint2* __restrict__ meta,
                                              float* __restrict__ dinv,
                                              unsigned int* __restrict__ srcs, int N) {
    __shared__ unsigned int fh[512];
    __shared__ unsigned int sc[512];
    const int k = blockIdx.x;
    const int t = threadIdx.x;
    const unsigned int ebase = bbase[k];
    const unsigned int ecnt = totals[k];
    fh[t] = 0u;
    __syncthreads();
    for (unsigned int j = t; j < ecnt; j += 512)
        atomicAdd(&fh[packed[ebase + j] & 511u], 1u);
    __syncthreads();
    unsigned int v = fh[t];
    sc[t] = v;
    __syncthreads();
    for (int d = 1; d < 512; d <<= 1) {
        unsigned int u = (t >= d) ? sc[t - d] : 0u;
        __syncthreads();
        sc[t] += u;
        __syncthreads();
    }
    const unsigned int excl = sc[t] - v;
    const int node = (k << 9) + t;
    if (node < N) {
        meta[node] = make_uint2(ebase + excl, v);
        dinv[node] = rsqrtf((float)v + 1.0f);  // +1 self loop
    }
    __syncthreads();
    fh[t] = excl;  // reuse as cursor
    __syncthreads();
    for (unsigned int j = t; j < ecnt; j += 512) {
        unsigned int p = packed[ebase + j];
        unsigned int pos = atomicAdd(&fh[p & 511u], 1u);
        srcs[ebase + pos] = (p >> 9) << 7;  // byte offset of source row
    }
}

// MFMA GEMM: G16[r][c] = bf16((X[r,:] @ W[:,c]) * dinv[r])
template <bool BF16IN>
__global__ __launch_bounds__(256) void gemm_mfma_k(const void* __restrict__ Xv,
                                                   const float* __restrict__ W,
                                                   const float* __restrict__ dinv,
                                                   unsigned short* __restrict__ G16, int N) {
    const int lane = threadIdx.x & 63;
    const int col = lane & 15;
    const int kg = lane >> 4;  // 0..3
    bf16x8 wf[4][2];
#pragma unroll
    for (int t = 0; t < 4; ++t)
#pragma unroll
        for (int s = 0; s < 2; ++s)
#pragma unroll
            for (int e = 0; e < 8; ++e)
                wf[t][s][e] = (short)(f2bf_r(W[(s * 32 + kg * 8 + e) * 64 + t * 16 + col]) >> 16);

    const int wid = blockIdx.x * (blockDim.x >> 6) + (threadIdx.x >> 6);
    const int nw = gridDim.x * (blockDim.x >> 6);
    const int nrb = (N + 15) >> 4;
    for (int rb = wid; rb < nrb; rb += nw) {
        const int arow = rb * 16 + col;
        bf16x8 af[2];
        if (BF16IN) {
            const unsigned short* X = (const unsigned short*)Xv;
            const unsigned short* p = X + (size_t)arow * 64 + kg * 8;
            af[0] = *(const bf16x8*)p;
            af[1] = *(const bf16x8*)(p + 32);
        } else {
            const float* X = (const float*)Xv;
            const float4* p = (const float4*)(X + (size_t)arow * 64 + kg * 8);
            float4 q0 = p[0], q1 = p[1], q2 = p[8], q3 = p[9];
            af[0][0] = (short)(f2bf_r(q0.x) >> 16); af[0][1] = (short)(f2bf_r(q0.y) >> 16);
            af[0][2] = (short)(f2bf_r(q0.z) >> 16); af[0][3] = (short)(f2bf_r(q0.w) >> 16);
            af[0][4] = (short)(f2bf_r(q1.x) >> 16); af[0][5] = (short)(f2bf_r(q1.y) >> 16);
            af[0][6] = (short)(f2bf_r(q1.z) >> 16); af[0][7] = (short)(f2bf_r(q1.w) >> 16);
            af[1][0] = (short)(f2bf_r(q2.x) >> 16); af[1][1] = (short)(f2bf_r(q2.y) >> 16);
            af[1][2] = (short)(f2bf_r(q2.z) >> 16); af[1][3] = (short)(f2bf_r(q2.w) >> 16);
            af[1][4] = (short)(f2bf_r(q3.x) >> 16); af[1][5] = (short)(f2bf_r(q3.y) >> 16);
            af[1][6] = (short)(f2bf_r(q3.z) >> 16); af[1][7] = (short)(f2bf_r(q3.w) >> 16);
        }
        f32x4 zero = {0.0f, 0.0f, 0.0f, 0.0f};
        f32x4 acc0 = zero, acc1 = zero, acc2 = zero, acc3 = zero;
        acc0 = __builtin_amdgcn_mfma_f32_16x16x32_bf16(af[0], wf[0][0], acc0, 0, 0, 0);
        acc1 = __builtin_amdgcn_mfma_f32_16x16x32_bf16(af[0], wf[1][0], acc1, 0, 0, 0);
        acc2 = __builtin_amdgcn_mfma_f32_16x16x32_bf16(af[0], wf[2][0], acc2, 0, 0, 0);
        acc3 = __builtin_amdgcn_mfma_f32_16x16x32_bf16(af[0], wf[3][0], acc3, 0, 0, 0);
        acc0 = __builtin_amdgcn_mfma_f32_16x16x32_bf16(af[1], wf[0][1], acc0, 0, 0, 0);
        acc1 = __builtin_amdgcn_mfma_f32_16x16x32_bf16(af[1], wf[1][1], acc1, 0, 0, 0);
        acc2 = __builtin_amdgcn_mfma_f32_16x16x32_bf16(af[1], wf[2][1], acc2, 0, 0, 0);
        acc3 = __builtin_amdgcn_mfma_f32_16x16x32_bf16(af[1], wf[3][1], acc3, 0, 0, 0);
#pragma unroll
        for (int reg = 0; reg < 4; ++reg) {
            const int r = rb * 16 + kg * 4 + reg;
            if (r < N) {
                const float dv = dinv[r];
                unsigned short* gp = G16 + (size_t)r * 64 + col;
                gp[0]  = (unsigned short)(f2bf_r(acc0[reg] * dv) >> 16);
                gp[16] = (unsigned short)(f2bf_r(acc1[reg] * dv) >> 16);
                gp[32] = (unsigned short)(f2bf_r(acc2[reg] * dv) >> 16);
                gp[48] = (unsigned short)(f2bf_r(acc3[reg] * dv) >> 16);
            }
        }
    }
}

// Fused layer-1 agg + layer-2 GEMM. Block = 32 nodes.
// gather (as agg_k) -> H tile bf16 in LDS (slot XOR-swizzled) -> MFMA @ W2
// -> G2 = (H @ W2) * dinv (bf16). H never touches global memory.
__global__ __launch_bounds__(256) void agg_gemm_k(const char* __restrict__ Gb,
                                                  const uint2* __restrict__ meta,
                                                  const unsigned int* __restrict__ srcs,
                                                  const float* __restrict__ dinv,
                                                  const float* __restrict__ bias,
                                                  const float* __restrict__ W2,
                                                  unsigned short* __restrict__ G2,
                                                  int N) {
    __shared__ unsigned int slds[SCAP];
    __shared__ unsigned short hlds[32 * 64];  // 4KB H tile
    uint4* hlds4 = (uint4*)hlds;
    hlds4[threadIdx.x] = make_uint4(0u, 0u, 0u, 0u);  // zero incl. tail rows

    const int nodeBase = blockIdx.x * 32;
    const int nLast = min(nodeBase + 31, N - 1);
    const unsigned int base = meta[nodeBase].x;
    const uint2 lastm = meta[nLast];
    const unsigned int blen = lastm.x + lastm.y - base;
    for (unsigned int i = threadIdx.x; i < blen && i < SCAP; i += 256)
        slds[i] = srcs[base + i];
    __syncthreads();

    const int lane = threadIdx.x & 63;
    const int grp = lane >> 3;
    const int sub = lane & 7;
    const int node = nodeBase + (threadIdx.x >> 6) * 8 + grp;
    if (node < N) {
        const uint2 oc = meta[node];
        const unsigned int orel = oc.x - base;
        const unsigned int c = oc.y;
        const unsigned int suboff = (unsigned int)sub << 4;
#define LDSRC(i) ((i) < SCAP ? slds[i] : srcs[base + (i)])
        float a0 = 0.f, a1 = 0.f, a2 = 0.f, a3 = 0.f;
        float a4 = 0.f, a5 = 0.f, a6 = 0.f, a7 = 0.f;
#define ACCUM(v)                              \
    do {                                      \
        a0 += bflo((v).x); a1 += bfhi((v).x); \
        a2 += bflo((v).y); a3 += bfhi((v).y); \
        a4 += bflo((v).z); a5 += bfhi((v).z); \
        a6 += bflo((v).w); a7 += bfhi((v).w); \
    } while (0)
        unsigned int j = 0;
        for (; j + 4 <= c; j += 4) {
            unsigned int s0 = LDSRC(orel + j);
            unsigned int s1 = LDSRC(orel + j + 1);
            unsigned int s2 = LDSRC(orel + j + 2);
            unsigned int s3 = LDSRC(orel + j + 3);
            uint4 v0 = *(const uint4*)(Gb + (s0 | suboff));
            uint4 v1 = *(const uint4*)(Gb + (s1 | suboff));
            uint4 v2 = *(const uint4*)(Gb + (s2 | suboff));
            uint4 v3 = *(const uint4*)(Gb + (s3 | suboff));
            ACCUM(v0);
            ACCUM(v1);
            ACCUM(v2);
            ACCUM(v3);
        }
        for (; j < c; ++j) {
            unsigned int s = LDSRC(orel + j);
            uint4 v = *(const uint4*)(Gb + (s | suboff));
            ACCUM(v);
        }
        {  // self loop
            uint4 g = *(const uint4*)(Gb + (((unsigned int)node << 7) | suboff));
            ACCUM(g);
        }
#undef ACCUM
#undef LDSRC
        const float dv = dinv[node];
        const float4 b0 = ((const float4*)bias)[sub * 2];
        const float4 b1 = ((const float4*)bias)[sub * 2 + 1];
        float o0 = fmaxf(fmaf(a0, dv, b0.x), 0.0f);
        float o1 = fmaxf(fmaf(a1, dv, b0.y), 0.0f);
        float o2 = fmaxf(fmaf(a2, dv, b0.z), 0.0f);
        float o3 = fmaxf(fmaf(a3, dv, b0.w), 0.0f);
        float o4 = fmaxf(fmaf(a4, dv, b1.x), 0.0f);
        float o5 = fmaxf(fmaf(a5, dv, b1.y), 0.0f);
        float o6 = fmaxf(fmaf(a6, dv, b1.z), 0.0f);
        float o7 = fmaxf(fmaf(a7, dv, b1.w), 0.0f);
        uint4 out;
        out.x = (f2bf_r(o0) >> 16) | (f2bf_r(o1) & 0xFFFF0000u);
        out.y = (f2bf_r(o2) >> 16) | (f2bf_r(o3) & 0xFFFF0000u);
        out.z = (f2bf_r(o4) >> 16) | (f2bf_r(o5) & 0xFFFF0000u);
        out.w = (f2bf_r(o6) >> 16) | (f2bf_r(o7) & 0xFFFF0000u);
        const int row = node - nodeBase;
        hlds4[(row << 3) | (sub ^ (row & 7))] = out;  // swizzled store
    }
    __syncthreads();

    // MFMA phase: wave w -> rowhalf = w>>1, colpair = w&1 (2 col-tiles)
    const int wid = threadIdx.x >> 6;
    const int rowhalf = wid >> 1;
    const int colpair = wid & 1;
    const int col = lane & 15;
    const int kg = lane >> 4;
    bf16x8 wf[2][2];
#pragma unroll
    for (int ct = 0; ct < 2; ++ct)
#pragma unroll
        for (int s = 0; s < 2; ++s)
#pragma unroll
            for (int e = 0; e < 8; ++e)
                wf[ct][s][e] = (short)(f2bf_r(W2[(s * 32 + kg * 8 + e) * 64 +
                                                 colpair * 32 + ct * 16 + col]) >> 16);
    const int arow = rowhalf * 16 + col;
    const int slot0 = kg ^ (arow & 7);
    bf16x8 af0 = *(const bf16x8*)&hlds4[(arow << 3) | slot0];
    bf16x8 af1 = *(const bf16x8*)&hlds4[(arow << 3) | (slot0 ^ 4)];
    f32x4 zero = {0.0f, 0.0f, 0.0f, 0.0f};
    f32x4 acc0 = zero, acc1 = zero;
    acc0 = __builtin_amdgcn_mfma_f32_16x16x32_bf16(af0, wf[0][0], acc0, 0, 0, 0);
    acc1 = __builtin_amdgcn_mfma_f32_16x16x32_bf16(af0, wf[1][0], acc1, 0, 0, 0);
    acc0 = __builtin_amdgcn_mfma_f32_16x16x32_bf16(af1, wf[0][1], acc0, 0, 0, 0);
    acc1 = __builtin_amdgcn_mfma_f32_16x16x32_bf16(af1, wf[1][1], acc1, 0, 0, 0);
#pragma unroll
    for (int reg = 0; reg < 4; ++reg) {
        const int r = nodeBase + rowhalf * 16 + kg * 4 + reg;
        if (r < N) {
            const float dv = dinv[r];
            unsigned short* gp = G2 + (size_t)r * 64 + colpair * 32 + col;
            gp[0]  = (unsigned short)(f2bf_r(acc0[reg] * dv) >> 16);
            gp[16] = (unsigned short)(f2bf_r(acc1[reg] * dv) >> 16);
        }
    }
}

// pure agg (layer 2): H16[node] = relu(dinv*(G2[node] + sum_src G2[src]) + b)
__global__ __launch_bounds__(256) void agg_k(const char* __restrict__ Gb,
                                             const uint2* __restrict__ meta,
                                             const unsigned int* __restrict__ srcs,
                                             const float* __restrict__ dinv,
                                             const float* __restrict__ bias,
                                             uint4* __restrict__ H4, int N) {
    __shared__ unsigned int slds[SCAP];
    const int nodeBase = blockIdx.x * 32;
    const int nLast = min(nodeBase + 31, N - 1);
    const unsigned int base = meta[nodeBase].x;
    const uint2 lastm = meta[nLast];
    const unsigned int blen = lastm.x + lastm.y - base;
    for (unsigned int i = threadIdx.x; i < blen && i < SCAP; i += 256)
        slds[i] = srcs[base + i];
    __syncthreads();

    const int lane = threadIdx.x & 63;
    const int grp = lane >> 3;
    const int sub = lane & 7;
    const int node = nodeBase + (threadIdx.x >> 6) * 8 + grp;
    if (node >= N) return;
    const uint2 oc = meta[node];
    const unsigned int orel = oc.x - base;
    const unsigned int c = oc.y;
    const unsigned int suboff = (unsigned int)sub << 4;
#define LDSRC(i) ((i) < SCAP ? slds[i] : srcs[base + (i)])
    float a0 = 0.f, a1 = 0.f, a2 = 0.f, a3 = 0.f;
    float a4 = 0.f, a5 = 0.f, a6 = 0.f, a7 = 0.f;
#define ACCUM(v)                              \
    do {                                      \
        a0 += bflo((v).x); a1 += bfhi((v).x); \
        a2 += bflo((v).y); a3 += bfhi((v).y); \
        a4 += bflo((v).z); a5 += bfhi((v).z); \
        a6 += bflo((v).w); a7 += bfhi((v).w); \
    } while (0)
    unsigned int j = 0;
    for (; j + 4 <= c; j += 4) {
        unsigned int s0 = LDSRC(orel + j);
        unsigned int s1 = LDSRC(orel + j + 1);
        unsigned int s2 = LDSRC(orel + j + 2);
        unsigned int s3 = LDSRC(orel + j + 3);
        uint4 v0 = *(const uint4*)(Gb + (s0 | suboff));
        uint4 v1 = *(const uint4*)(Gb + (s1 | suboff));
        uint4 v2 = *(const uint4*)(Gb + (s2 | suboff));
        uint4 v3 = *(const uint4*)(Gb + (s3 | suboff));
        ACCUM(v0);
        ACCUM(v1);
        ACCUM(v2);
        ACCUM(v3);
    }
    for (; j < c; ++j) {
        unsigned int s = LDSRC(orel + j);
        uint4 v = *(const uint4*)(Gb + (s | suboff));
        ACCUM(v);
    }
    {  // self loop
        uint4 g = *(const uint4*)(Gb + (((unsigned int)node << 7) | suboff));
        ACCUM(g);
    }
#undef ACCUM
#undef LDSRC
    const float dv = dinv[node];
    const float4 b0 = ((const float4*)bias)[sub * 2];
    const float4 b1 = ((const float4*)bias)[sub * 2 + 1];
    float o0 = fmaxf(fmaf(a0, dv, b0.x), 0.0f);
    float o1 = fmaxf(fmaf(a1, dv, b0.y), 0.0f);
    float o2 = fmaxf(fmaf(a2, dv, b0.z), 0.0f);
    float o3 = fmaxf(fmaf(a3, dv, b0.w), 0.0f);
    float o4 = fmaxf(fmaf(a4, dv, b1.x), 0.0f);
    float o5 = fmaxf(fmaf(a5, dv, b1.y), 0.0f);
    float o6 = fmaxf(fmaf(a6, dv, b1.z), 0.0f);
    float o7 = fmaxf(fmaf(a7, dv, b1.w), 0.0f);
    uint4 out;
    out.x = (f2bf_r(o0) >> 16) | (f2bf_r(o1) & 0xFFFF0000u);
    out.y = (f2bf_r(o2) >> 16) | (f2bf_r(o3) & 0xFFFF0000u);
    out.z = (f2bf_r(o4) >> 16) | (f2bf_r(o5) & 0xFFFF0000u);
    out.w = (f2bf_r(o6) >> 16) | (f2bf_r(o7) & 0xFFFF0000u);
    H4[(size_t)node * 8 + sub] = out;
}

// fused mean-pool + FC: one block per graph; batch sorted.
__global__ __launch_bounds__(256) void graph_k(const unsigned int* __restrict__ H2,
                                               const int* __restrict__ batch,
                                               const float* __restrict__ Wfc,
                                               const float* __restrict__ bfc,
                                               float* __restrict__ out, int N) {
    __shared__ float sh[8 * 64];
    __shared__ float p[64];
    const int g = blockIdx.x;
    const int t = threadIdx.x;
    int lo = 0, hi = N;
    while (lo < hi) {
        int mid = (lo + hi) >> 1;
        if (batch[mid] < g) lo = mid + 1; else hi = mid;
    }
    const int start = lo;
    hi = N;
    while (lo < hi) {
        int mid = (lo + hi) >> 1;
        if (batch[mid] < g + 1) lo = mid + 1; else hi = mid;
    }
    const int end = lo;

    const int w = t >> 5;
    const int c = t & 31;
    float acc0 = 0.f, acc1 = 0.f;
    for (int i = start + w; i < end; i += 8) {
        unsigned int v = H2[(size_t)i * 32 + c];
        acc0 += bflo(v);
        acc1 += bfhi(v);
    }
    sh[w * 64 + 2 * c] = acc0;
    sh[w * 64 + 2 * c + 1] = acc1;
    __syncthreads();
    if (t < 64) {
        float s = 0.f;
#pragma unroll
        for (int i = 0; i < 8; ++i) s += sh[i * 64 + t];
        p[t] = s / (float)max(end - start, 1);
    }
    __syncthreads();
    if (t < 10) {
        float a = bfc[t];
#pragma unroll
        for (int k = 0; k < 64; ++k) a = fmaf(p[k], Wfc[k * 10 + t], a);
        out[g * 10 + t] = a;
    }
}

extern "C" void kernel_launch(void* const* d_in, const int* in_sizes, int n_in,
                              void* d_out, int out_size, void* d_ws, size_t ws_size,
                              hipStream_t stream) {
    const float* x     = (const float*)d_in[0];
    const float* W1    = (const float*)d_in[1];
    const float* b1    = (const float*)d_in[2];
    const float* W2    = (const float*)d_in[3];
    const float* b2    = (const float*)d_in[4];
    const float* Wfc   = (const float*)d_in[5];
    const float* bfc   = (const float*)d_in[6];
    const int*   eidx  = (const int*)d_in[7];
    const int*   batch = (const int*)d_in[8];

    const int N = in_sizes[0] / 64;
    const int E = in_sizes[7] / 2;
    const int G = out_size / 10;
    const int* erow = eidx;      // sources
    const int* ecol = eidx + E;  // destinations

    const int nbuck = (N + 511) >> 9;  // coarse buckets (<= 256)
    const int chunk = (((E + NBLK_SORT - 1) / NBLK_SORT) + 3) & ~3;

    char* ws = (char*)d_ws;
    size_t off = 0;
    auto alloc = [&](size_t bytes) -> void* {
        void* p = ws + off;
        off = (off + bytes + 511) & ~(size_t)511;
        return p;
    };
    uint2*        meta   = (uint2*)alloc((size_t)N * 8);
    float*        dinv   = (float*)alloc((size_t)N * 4);
    unsigned int* totals = (unsigned int*)alloc((size_t)nbuck * 4);
    unsigned int* bbase  = (unsigned int*)alloc((size_t)nbuck * 4);
    unsigned int* srcs   = (unsigned int*)alloc((size_t)E * 4);
    unsigned short* G16  = (unsigned short*)alloc((size_t)N * 64 * 2);
    unsigned short* G2   = (unsigned short*)alloc((size_t)N * 64 * 2);
    unsigned short* H16  = (unsigned short*)alloc((size_t)N * 64 * 2);
    unsigned int* bhist  = (unsigned int*)alloc((size_t)NBLK_SORT * 256 * 4);

    // packed aliases H16 (dead before H16 is first written by agg_k)
    unsigned int* packed = (unsigned int*)H16;

    // --- CSR build ---
    hist_k<<<NBLK_SORT, 256, 0, stream>>>(ecol, bhist, E, chunk, nbuck);
    scatter2_k<<<NBLK_SORT, 256, 0, stream>>>(erow, ecol, bhist, bbase, totals,
                                              packed, E, chunk, nbuck);
    fine_k<<<nbuck, 512, 0, stream>>>(packed, bbase, totals, meta, dinv, srcs, N);

    const int aggB = (N + 31) / 32;

    // --- layer 1 GEMM ---
    gemm_mfma_k<false><<<512, 256, 0, stream>>>(x, W1, dinv, G16, N);
    // --- layer 1 agg + layer 2 GEMM (fused) ---
    agg_gemm_k<<<aggB, 256, 0, stream>>>((const char*)G16, meta, srcs, dinv, b1,
                                         W2, G2, N);
    // --- layer 2 agg ---
    agg_k<<<aggB, 256, 0, stream>>>((const char*)G2, meta, srcs, dinv, b2,
                                    (uint4*)H16, N);
    // --- fused mean-pool + FC ---
    graph_k<<<G, 256, 0, stream>>>((const unsigned int*)H16, batch, Wfc, bfc,
                                   (float*)d_out, N);
}